// Round 16
// baseline (576.521 us; speedup 1.0000x reference)
//
#include <hip/hip_runtime.h>

#define B_  64
#define T_  256
#define H_  512
#define NH_ 8
#define DH_ 64
#define M_  16384
#define SL  262144  // 512*512 elements per weight slot

typedef float  f32x4 __attribute__((ext_vector_type(4)));
typedef float  f32x2 __attribute__((ext_vector_type(2)));
typedef __bf16 b16x8 __attribute__((ext_vector_type(8)));
typedef __bf16 b16x4 __attribute__((ext_vector_type(4)));
typedef __bf16 b16x2 __attribute__((ext_vector_type(2)));

__device__ __forceinline__ void gload16(const void* g, void* l) {
  __builtin_amdgcn_global_load_lds((const __attribute__((address_space(1))) void*)g,
                                   (__attribute__((address_space(3))) void*)l, 16, 0, 0);
}

// ---------------- fp32 -> bf16 convert ----------------
__global__ __launch_bounds__(256) void cvt_f32_bf16_k(const float* __restrict__ in,
                                                      __bf16* __restrict__ out) {
  size_t i = ((size_t)blockIdx.x * 256 + threadIdx.x) * 4;
  f32x4 v = *(const f32x4*)(in + i);
  b16x4 o;
  o[0] = (__bf16)v[0]; o[1] = (__bf16)v[1]; o[2] = (__bf16)v[2]; o[3] = (__bf16)v[3];
  *(b16x4*)(out + i) = o;
}

// ---------------- batched weight transpose (+ optional scale): up to 15 slices ----------------
struct TP15 { const float* src[15]; int slot[15]; float scl[15]; };
__global__ __launch_bounds__(256) void transpose_cvt15(TP15 p, __bf16* __restrict__ wT) {
  __shared__ float tile[32][33];
  const float* in = p.src[blockIdx.z];
  __bf16* out = wT + (size_t)p.slot[blockIdx.z] * SL;
  const float scl = p.scl[blockIdx.z];
  int c0 = blockIdx.x * 32, r0 = blockIdx.y * 32;
  int tx = threadIdx.x & 31, ty = threadIdx.x >> 5;
  for (int yy = ty; yy < 32; yy += 8)
    tile[yy][tx] = in[(size_t)(r0 + yy) * 512 + c0 + tx];
  __syncthreads();
  for (int yy = ty; yy < 32; yy += 8)
    out[(size_t)(c0 + yy) * 512 + r0 + tx] = (__bf16)(tile[tx][yy] * scl);
}

// ---------------- generic transpose + convert (for W1: 2048x512) ----------------
__global__ __launch_bounds__(256) void transpose_cvt(const float* __restrict__ in,
                                                     __bf16* __restrict__ out, int R, int C) {
  __shared__ float tile[32][33];
  int c0 = blockIdx.x * 32, r0 = blockIdx.y * 32;
  int tx = threadIdx.x & 31, ty = threadIdx.x >> 5;
  for (int yy = ty; yy < 32; yy += 8)
    tile[yy][tx] = in[(size_t)(r0 + yy) * C + c0 + tx];
  __syncthreads();
  for (int yy = ty; yy < 32; yy += 8)
    out[(size_t)(c0 + yy) * R + r0 + tx] = (__bf16)tile[tx][yy];
}

// ---------------- emotion K/V: (7,512) = emo @ W + b ----------------
__global__ __launch_bounds__(512) void emo_kv(const float* __restrict__ emo,
                                              const float* __restrict__ Wk, const float* __restrict__ bk,
                                              const float* __restrict__ Wv, const float* __restrict__ bv,
                                              float* __restrict__ kout, float* __restrict__ vout) {
  int e = blockIdx.x, n = threadIdx.x;
  const float* W = blockIdx.y ? Wv : Wk;
  const float* bb = blockIdx.y ? bv : bk;
  float* o = blockIdx.y ? vout : kout;
  float acc = 0.f;
  for (int kk = 0; kk < 512; ++kk) acc += emo[e * 512 + kk] * W[kk * 512 + n];
  o[e * 512 + n] = acc + bb[n];
}

// ---------------- sentiment precompute (bf16, scale folded) ----------------
__global__ __launch_bounds__(512) void sentprep(const float* __restrict__ Wq,
                                                const float* __restrict__ bq,
                                                const float* __restrict__ Wo,
                                                const float* __restrict__ kemo,
                                                const float* __restrict__ vemo,
                                                __bf16* __restrict__ Wqk_bf,
                                                __bf16* __restrict__ VWo_bf,
                                                float* __restrict__ sbias) {
  const int he = blockIdx.x, h = he / 7, e = he % 7;
  const int t = threadIdx.x;
  const float* kp = kemo + e * 512 + h * 64;
  const float* wqr = Wq + (size_t)t * 512 + h * 64;
  float a = 0.f;
#pragma unroll 8
  for (int d = 0; d < 64; ++d) a += wqr[d] * kp[d];
  Wqk_bf[he * 512 + t] = (__bf16)(a * 0.125f);
  const float* vp = vemo + e * 512 + h * 64;
  float v = 0.f;
#pragma unroll 8
  for (int d = 0; d < 64; ++d) v += vp[d] * Wo[(size_t)(h * 64 + d) * 512 + t];
  VWo_bf[t * 64 + h * 8 + e] = (__bf16)v;
  if (e == 0) VWo_bf[t * 64 + h * 8 + 7] = (__bf16)0.f;
  if (t == 0) {
    float s = 0.f;
    for (int d = 0; d < 64; ++d) s += bq[h * 64 + d] * kp[d];
    sbias[he] = s * 0.125f;
  }
}

__global__ __launch_bounds__(512) void sentpad(__bf16* __restrict__ Wqk_bf,
                                               float* __restrict__ sbias) {
  int r = 56 + blockIdx.x;
  Wqk_bf[r * 512 + threadIdx.x] = (__bf16)0.f;
  if (threadIdx.x == 0) sbias[r] = 0.f;
}

// ---------------- bias helpers; pair layout [bq_{2p}, bk_{2p}*.125, bq_{2p+1}, bk_{2p+1}*.125] ----
__global__ __launch_bounds__(512) void concat_qk_bias(const float* __restrict__ bq,
                                                      const float* __restrict__ bk,
                                                      float* __restrict__ out) {
  int i = blockIdx.x, t = threadIdx.x;
  int base = (i >> 1) * 2048 + (i & 1) * 1024;
  out[base + t]       = bq[i * 512 + t];
  out[base + 512 + t] = bk[i * 512 + t] * 0.125f;
}

__global__ __launch_bounds__(256) void bias2_p1(const float* __restrict__ bo,
                                                const float* __restrict__ W1,
                                                float* __restrict__ partial) {
  int p = blockIdx.x, t = threadIdx.x;
  float a0 = 0.f, a1 = 0.f;
  for (int g = p * 128; g < p * 128 + 128; ++g) {
    float bg = bo[g];
    a0 += bg * W1[(size_t)g * 512 + t];
    a1 += bg * W1[(size_t)g * 512 + 256 + t];
  }
  partial[p * 512 + t] = a0;
  partial[p * 512 + 256 + t] = a1;
}

__global__ __launch_bounds__(256) void bias2_p2(const float* __restrict__ b1,
                                                const float* __restrict__ partial,
                                                float* __restrict__ out) {
  int o = blockIdx.x * 256 + threadIdx.x;
  float acc = b1[o];
#pragma unroll
  for (int p = 0; p < 16; ++p) acc += partial[p * 512 + o];
  out[o] = acc;
}

// ---------------- MFMA GEMM 256x128, 8 waves, BK=32, 2-phase, 48KB LDS ----
template<bool OB, int BM, int SW>
__global__ __launch_bounds__(512, 2) void gemm32(const __bf16* __restrict__ A,
                                                 const __bf16* __restrict__ Bt,
                                                 const float* __restrict__ bias,
                                                 void* __restrict__ Cv,
                                                 int N, int K, int lda, int ldc) {
  __shared__ __attribute__((aligned(16))) __bf16 As[2][256 * 32];
  __shared__ __attribute__((aligned(16))) __bf16 Bs[2][128 * 32];
  const int gx = gridDim.x;
  const int bid = blockIdx.y * gx + blockIdx.x;
  int bx, by;
  if (SW == 0) {
    const int nwg = gx * gridDim.y;
    const int cpx = nwg >> 3;
    const int swz = (bid & 7) * cpx + (bid >> 3);
    bx = swz % gx; by = swz / gx;
  } else {
    const int gxc = gx >> 3;
    const int u = bid >> 3, c = bid & 7;
    bx = c * gxc + u % gxc;
    by = u / gxc;
  }
  const int tid = threadIdx.x, lane = tid & 63, wid = tid >> 6;
  const int wr = wid >> 2, wc = wid & 3;
  const int m0 = by * 256, n0 = bx * 128;
  const int l15 = lane & 15, l16 = lane >> 4;
  const int ra = tid >> 2;
  const int xsl = (tid & 3) ^ ((ra >> 1) & 3);
  const int nt = K >> 5;
  f32x4 acc[8][2] = {};

#define STAGE32(buf, k0)                                                             \
  { char* aw = (char*)&As[buf][0];                                                   \
    char* bw = (char*)&Bs[buf][0];                                                   \
    gload16(A + (size_t)(m0 + ra) * lda + (k0) + xsl * 8, aw + tid * 16);            \
    gload16(A + (size_t)(m0 + 128 + ra) * lda + (k0) + xsl * 8, aw + (512 + tid) * 16); \
    gload16(Bt + (size_t)(n0 + ra) * K + (k0) + xsl * 8, bw + tid * 16); }

#define CMP32(buf)                                                                   \
  { const char* Ac = (const char*)&As[buf][0];                                       \
    const char* Bc = (const char*)&Bs[buf][0];                                       \
    const int swb = ((l16 ^ ((l15 >> 1) & 3)) << 4);                                 \
    b16x8 af[8], bf[2];                                                              \
    _Pragma("unroll")                                                                \
    for (int m = 0; m < 8; ++m)                                                      \
      af[m] = *(const b16x8*)(Ac + (wr * 128 + m * 16 + l15) * 64 + swb);            \
    _Pragma("unroll")                                                                \
    for (int n = 0; n < 2; ++n)                                                      \
      bf[n] = *(const b16x8*)(Bc + (wc * 32 + n * 16 + l15) * 64 + swb);             \
    __builtin_amdgcn_s_setprio(1);                                                   \
    _Pragma("unroll")                                                                \
    for (int m = 0; m < 8; ++m)                                                      \
      _Pragma("unroll")                                                              \
      for (int n = 0; n < 2; ++n)                                                    \
        acc[m][n] = __builtin_amdgcn_mfma_f32_16x16x32_bf16(af[m], bf[n], acc[m][n], 0, 0, 0); \
    __builtin_amdgcn_s_setprio(0); }

  STAGE32(0, 0);
  int cur = 0;
  for (int t = 0; t < nt; ++t) {
    if (t + 1 < nt) {
      STAGE32(cur ^ 1, (t + 1) * 32);
      asm volatile("s_waitcnt vmcnt(3)" ::: "memory");
    } else {
      asm volatile("s_waitcnt vmcnt(0)" ::: "memory");
    }
    __builtin_amdgcn_s_barrier();
    CMP32(cur);
    asm volatile("s_waitcnt lgkmcnt(0)" ::: "memory");
    __builtin_amdgcn_s_barrier();
    cur ^= 1;
  }
#undef STAGE32
#undef CMP32

  const int rb = m0 + wr * 128 + l16 * 4;
  const int cb = n0 + wc * 32 + l15;
#pragma unroll
  for (int n = 0; n < 2; ++n) {
    int gc = cb + n * 16;
    float bc = (BM == 1) ? bias[gc] : 0.0f;
#pragma unroll
    for (int m = 0; m < 8; ++m) {
#pragma unroll
      for (int rr = 0; rr < 4; ++rr) {
        int gr = rb + m * 16 + rr;
        float val = acc[m][n][rr] + ((BM == 2) ? bias[gr] : bc);
        if (OB) ((__bf16*)Cv)[(size_t)gr * ldc + gc] = (__bf16)val;
        else    ((float*)Cv)[(size_t)gr * ldc + gc] = val;
      }
    }
  }
}

// ---------------- MFMA GEMM 128x64 (proven; small/odd shapes, z-batched) ----------------
template<bool OB, int BM, int SW>
__global__ __launch_bounds__(256) void gemm_bt64(const __bf16* __restrict__ A,
                                                 const __bf16* __restrict__ Bt,
                                                 const float* __restrict__ bias,
                                                 void* __restrict__ Cv,
                                                 int N, int K, int lda, int ldc,
                                                 size_t zA, size_t zB, size_t zC) {
  __shared__ __attribute__((aligned(16))) __bf16 As[128 * 32];
  __shared__ __attribute__((aligned(16))) __bf16 Bs[64 * 32];
  A  += (size_t)blockIdx.z * zA;
  Bt += (size_t)blockIdx.z * zB;
  char* Cb = (char*)Cv + (size_t)blockIdx.z * zC * (OB ? 2 : 4);
  const int gx = gridDim.x;
  const int bid = blockIdx.y * gx + blockIdx.x;
  int bx, by;
  if (SW == 0) {
    const int nwg = gx * gridDim.y;
    const int cpx = nwg >> 3;
    const int swz = (bid & 7) * cpx + (bid >> 3);
    bx = swz % gx; by = swz / gx;
  } else {
    const int gxc = gx >> 3;
    const int u = bid >> 3, c = bid & 7;
    bx = c * gxc + u % gxc;
    by = u / gxc;
  }
  const int tid = threadIdx.x, lane = tid & 63, wid = tid >> 6;
  const int m0 = by * 128, n0 = bx * 64;
  const int l15 = lane & 15, l16 = lane >> 4;
  const int r0 = tid >> 2, o0 = (tid & 3) * 8;
  const __bf16* a0 = A + (size_t)(m0 + r0) * lda + o0;
  const __bf16* a1 = A + (size_t)(m0 + 64 + r0) * lda + o0;
  const __bf16* bp0 = Bt + (size_t)(n0 + r0) * K + o0;
  char* AsW = (char*)As + wid * 1024;
  char* BsW = (char*)Bs + wid * 1024;
  f32x4 acc[2][4] = {};
  for (int k0 = 0; k0 < K; k0 += 32) {
    gload16(a0 + k0, AsW);
    gload16(a1 + k0, AsW + 4096);
    gload16(bp0 + k0, BsW);
    __syncthreads();
    b16x8 af[2], bf[4];
#pragma unroll
    for (int m = 0; m < 2; ++m) af[m] = *(const b16x8*)&As[(wid * 32 + m * 16 + l15) * 32 + l16 * 8];
#pragma unroll
    for (int n = 0; n < 4; ++n) bf[n] = *(const b16x8*)&Bs[(n * 16 + l15) * 32 + l16 * 8];
#pragma unroll
    for (int m = 0; m < 2; ++m)
#pragma unroll
      for (int n = 0; n < 4; ++n)
        acc[m][n] = __builtin_amdgcn_mfma_f32_16x16x32_bf16(af[m], bf[n], acc[m][n], 0, 0, 0);
    __syncthreads();
  }
  const int rbase = m0 + wid * 32 + l16 * 4;
  const int cb = n0 + l15;
#pragma unroll
  for (int n = 0; n < 4; ++n) {
    int gc = cb + n * 16;
    float bc = (BM == 1) ? bias[gc] : 0.0f;
#pragma unroll
    for (int m = 0; m < 2; ++m) {
#pragma unroll
      for (int rr = 0; rr < 4; ++rr) {
        int gr = rbase + m * 16 + rr;
        float val = acc[m][n][rr] + ((BM == 2) ? bias[gr] : bc);
        if (OB) ((__bf16*)Cb)[(size_t)gr * ldc + gc] = (__bf16)val;
        else    ((float*)Cb)[(size_t)gr * ldc + gc] = val;
      }
    }
  }
}

// ---------------- per-(token,head) 7-wide softmax ----------------
__global__ __launch_bounds__(256) void softmax7(const float* __restrict__ scores,
                                                __bf16* __restrict__ P) {
  int idx = blockIdx.x * 256 + threadIdx.x;
  int m = idx >> 3, h = idx & 7;
  const float* s = scores + (size_t)m * 64 + h * 7;
  float v[7], mx = -3.4e38f;
#pragma unroll
  for (int e = 0; e < 7; ++e) { v[e] = s[e]; mx = fmaxf(mx, v[e]); }
  float sum = 0.f;
#pragma unroll
  for (int e = 0; e < 7; ++e) { v[e] = __expf(v[e] - mx); sum += v[e]; }
  float inv = 1.f / sum;
  __bf16* o = P + (size_t)m * 64 + h * 8;
#pragma unroll
  for (int e = 0; e < 7; ++e) o[e] = (__bf16)(v[e] * inv);
  o[7] = (__bf16)0.f;
}

// ---------------- bf16 pre + fp32 res LayerNorm -> bf16 ----------------
__global__ __launch_bounds__(256) void ln1_bf(const __bf16* __restrict__ pre,
                                              const float* __restrict__ res,
                                              const float* __restrict__ g,
                                              const float* __restrict__ bt,
                                              __bf16* __restrict__ ob) {
  int row = blockIdx.x, t = threadIdx.x;
  size_t base = (size_t)row * 512;
  b16x2 p2 = *(const b16x2*)(pre + base + 2 * t);
  f32x2 r2 = *(const f32x2*)(res + base + 2 * t);
  float v0 = (float)p2[0] + r2[0];
  float v1 = (float)p2[1] + r2[1];
  float s = v0 + v1, q = v0 * v0 + v1 * v1;
#pragma unroll
  for (int off = 32; off; off >>= 1) { s += __shfl_xor(s, off); q += __shfl_xor(q, off); }
  __shared__ float ls[4], lq[4];
  int wid = t >> 6, lane = t & 63;
  if (lane == 0) { ls[wid] = s; lq[wid] = q; }
  __syncthreads();
  s = ls[0] + ls[1] + ls[2] + ls[3];
  q = lq[0] + lq[1] + lq[2] + lq[3];
  float mean = s * (1.f / 512.f);
  float var = q * (1.f / 512.f) - mean * mean;
  float rstd = rsqrtf(fmaxf(var, 0.f) + 1e-12f);
  b16x2 o;
  o[0] = (__bf16)((v0 - mean) * rstd * g[2 * t] + bt[2 * t]);
  o[1] = (__bf16)((v1 - mean) * rstd * g[2 * t + 1] + bt[2 * t + 1]);
  *(b16x2*)(ob + base + 2 * t) = o;
}

// ---------------- bf16+bf16 residual LayerNorm ----------------
__global__ __launch_bounds__(256) void ln2_bb(const __bf16* __restrict__ pre,
                                              const __bf16* __restrict__ res,
                                              const float* __restrict__ g,
                                              const float* __restrict__ bt,
                                              __bf16* __restrict__ ob) {
  int row = blockIdx.x, t = threadIdx.x;
  size_t base = (size_t)row * 512;
  b16x2 p2 = *(const b16x2*)(pre + base + 2 * t);
  b16x2 r2 = *(const b16x2*)(res + base + 2 * t);
  float v0 = (float)p2[0] + (float)r2[0];
  float v1 = (float)p2[1] + (float)r2[1];
  float s = v0 + v1, q = v0 * v0 + v1 * v1;
#pragma unroll
  for (int off = 32; off; off >>= 1) { s += __shfl_xor(s, off); q += __shfl_xor(q, off); }
  __shared__ float ls[4], lq[4];
  int wid = t >> 6, lane = t & 63;
  if (lane == 0) { ls[wid] = s; lq[wid] = q; }
  __syncthreads();
  s = ls[0] + ls[1] + ls[2] + ls[3];
  q = lq[0] + lq[1] + lq[2] + lq[3];
  float mean = s * (1.f / 512.f);
  float var = q * (1.f / 512.f) - mean * mean;
  float rstd = rsqrtf(fmaxf(var, 0.f) + 1e-12f);
  b16x2 o;
  o[0] = (__bf16)((v0 - mean) * rstd * g[2 * t] + bt[2 * t]);
  o[1] = (__bf16)((v1 - mean) * rstd * g[2 * t + 1] + bt[2 * t + 1]);
  *(b16x2*)(ob + base + 2 * t) = o;
}

// ---------------- fused masked attention: BARRIER-FREE wave-private structure ----------------
// grid (bh=512, z=2); branch = PAIR*2 + z. Each wave owns 16 full q-rows (all 256 cols):
// row-sum is wave-local, P in a wave-private LDS strip, rinv stays in registers.
// One __syncthreads total (after K stage). Fixed-max softmax as R15.
template<int PAIR>
__global__ __launch_bounds__(256) void attn_branch(const __bf16* __restrict__ qk,
                                                   const __bf16* __restrict__ vt,
                                                   __bf16* __restrict__ ctx,
                                                   const int* __restrict__ lengths,
                                                   const int* __restrict__ speakers) {
  __shared__ __attribute__((aligned(16))) __bf16 Ks[256 * 64];     // 32 KB, read-only post-stage
  __shared__ __attribute__((aligned(16))) __bf16 Ps[4][16 * 264];  // wave-private P strips
  __shared__ int spk[256];
  const int sqk = 2048, so = 2048;
  const int tid = threadIdx.x, lane = tid & 63, wid = tid >> 6;
  const int l15 = lane & 15, l16 = lane >> 4;
  const int bh = blockIdx.x, z = blockIdx.y;
  const int BR = PAIR * 2 + z;
  const int b = bh >> 3, h = bh & 7;
  const __bf16* qp = qk + z * 1024;
  const __bf16* kp = qp + 512;
  const __bf16* vb2 = vt + (size_t)(BR * 512 + h * DH_) * M_ + b * T_;
  __bf16* ctxp = ctx + (size_t)BR * 512;
  const __bf16 CB = (__bf16)10000.0f, mCB = (__bf16)(-10000.0f), ZB = (__bf16)0.0f, OB1 = (__bf16)1.0f;
  const float CBF = (float)CB;
  const float MSTAR = (BR == 1) ? 16.0f : CBF + 16.0f;

  {  // stage all 256 K rows once (xor-pre-swizzled source, linear LDS dest)
    const size_t kb0 = (size_t)(b * T_) * sqk + h * DH_;
    const int rsub = lane >> 3, slot = lane & 7;
#pragma unroll
    for (int j = 0; j < 8; ++j) {
      int row = (j * 4 + wid) * 8 + rsub;
      gload16(kp + kb0 + (size_t)row * sqk + ((slot ^ (row & 7)) * 8),
              (char*)Ks + (j * 4 + wid) * 1024);
    }
  }
  spk[tid] = speakers[b * T_ + tid];
  __syncthreads();   // the ONLY block barrier
  const int L = lengths[b];
  __bf16* PsW = &Ps[wid][0];

  // prefetch Q for iter 0 (wave's rows: wid*16 + l15)
  b16x8 af0, af1;
  {
    const __bf16* qr = qp + (size_t)(b * T_ + wid * 16 + l15) * sqk + h * DH_;
    af0 = *(const b16x8*)(qr + l16 * 8);
    af1 = *(const b16x8*)(qr + 32 + l16 * 8);
  }

  for (int it = 0; it < 4; ++it) {
    const int q0 = it * 64 + wid * 16;   // this wave's 16-row block
    b16x8 afU = {};
    if (BR != 1 && l16 == 0) {
      int jA = q0 + l15;
      bool rv = jA < L;
      afU[0] = rv ? OB1 : ZB;
      afU[1] = (rv && spk[jA]) ? OB1 : ZB;
      afU[2] = (BR == 0) ? OB1 : (rv ? ZB : OB1);
    }

    // QK^T + mask over ALL 16 col-tiles (wave-complete rows)
    f32x4 sa[16];
#pragma unroll
    for (int nn = 0; nn < 16; ++nn) {
      int krw = nn * 16 + l15;
      b16x8 b0 = *(const b16x8*)((char*)Ks + krw * 128 + ((l16 ^ (krw & 7)) * 16));
      f32x4 zv = {};
      zv = __builtin_amdgcn_mfma_f32_16x16x32_bf16(af0, b0, zv, 0, 0, 0);
      b16x8 b1 = *(const b16x8*)((char*)Ks + krw * 128 + (((4 + l16) ^ (krw & 7)) * 16));
      sa[nn] = __builtin_amdgcn_mfma_f32_16x16x32_bf16(af1, b1, zv, 0, 0, 0);
      if (BR != 1) {
        b16x8 w = {};
        if (l16 == 0) {
          bool cv = krw < L;
          int sc = spk[krw];
          if (BR == 0) {
            w[2] = cv ? CB : ZB;
          } else if (BR == 2) {
            w[0] = sc ? ZB : CB;
            w[1] = sc ? CB : mCB;
            w[2] = CB;
          } else {
            w[0] = (cv && sc) ? CB : ZB;
            w[1] = cv ? (sc ? mCB : CB) : ZB;
            w[2] = CB;
          }
        }
        sa[nn] = __builtin_amdgcn_mfma_f32_16x16x32_bf16(afU, w, sa[nn], 0, 0, 0);
      }
    }

    // prefetch Q for next iter (hides under softmax+PV)
    if (it + 1 < 4) {
      const __bf16* qr = qp + (size_t)(b * T_ + (it + 1) * 64 + wid * 16 + l15) * sqk + h * DH_;
      af0 = *(const b16x8*)(qr + l16 * 8);
      af1 = *(const b16x8*)(qr + 32 + l16 * 8);
    }

    // fixed-max softmax: exp + wave-local row-sum; rinv stays in registers
    float rinv[4];
#pragma unroll
    for (int rr = 0; rr < 4; ++rr) {
      const int j = q0 + l16 * 4 + rr;
      const bool rv = j < L;
      float s = 0.f;
#pragma unroll
      for (int nn = 0; nn < 16; ++nn) {
        float v = sa[nn][rr];
        if (BR == 1) {
          int c = nn * 16 + l15;
          int dj = j - c;
          bool ok = (c < L) && (dj <= 2) && (dj >= -2);
          v += (ok || !rv) ? 0.0f : -10000.0f;
        }
        float e = __expf(v - MSTAR);
        sa[nn][rr] = e;
        s += e;
      }
      s += __shfl_xor(s, 1); s += __shfl_xor(s, 2); s += __shfl_xor(s, 4); s += __shfl_xor(s, 8);
      rinv[rr] = 1.0f / s;
    }

    // P -> wave-private LDS strip (same-wave write->read, no barrier)
#pragma unroll
    for (int rr = 0; rr < 4; ++rr)
#pragma unroll
      for (int nn = 0; nn < 16; ++nn)
        PsW[(l16 * 4 + rr) * 264 + nn * 16 + l15] = (__bf16)sa[nn][rr];

    // PV: A from own P strip, B = V^T from global (L1/L2-warm)
    f32x4 oa[4] = {};
#pragma unroll
    for (int kt = 0; kt < 8; ++kt) {
      b16x8 afp = *(const b16x8*)&PsW[l15 * 264 + kt * 32 + l16 * 8];
#pragma unroll
      for (int n = 0; n < 4; ++n) {
        b16x8 bfr = *(const b16x8*)(vb2 + (size_t)(n * 16 + l15) * M_ + kt * 32 + l16 * 8);
        oa[n] = __builtin_amdgcn_mfma_f32_16x16x32_bf16(afp, bfr, oa[n], 0, 0, 0);
      }
    }
#pragma unroll
    for (int rr = 0; rr < 4; ++rr) {
      int row = q0 + l16 * 4 + rr;
#pragma unroll
      for (int n = 0; n < 4; ++n)
        ctxp[(size_t)(b * T_ + row) * so + h * DH_ + n * 16 + l15]
            = (__bf16)(oa[n][rr] * rinv[rr]);
    }
  }
}

// ============================================================================
extern "C" void kernel_launch(void* const* d_in, const int* in_sizes, int n_in,
                              void* d_out, int out_size, void* d_ws, size_t ws_size,
                              hipStream_t stream) {
  const float* x        = (const float*)d_in[0];
  const int*   lengths  = (const int*)d_in[1];
  const int*   speakers = (const int*)d_in[2];
  const float* emo      = (const float*)d_in[3];
  const float* t_Wq = (const float*)d_in[4];
  const float* t_bq = (const float*)d_in[5];
  const float* t_Wk = (const float*)d_in[6];
  const float* t_bk = (const float*)d_in[7];
  const float* t_Wv = (const float*)d_in[8];
  const float* t_bv = (const float*)d_in[9];
  const float* t_Wo = (const float*)d_in[10];
  const float* t_bo = (const float*)d_in[11];
  const float* t_ln_g = (const float*)d_in[12];
  const float* t_ln_b = (const float*)d_in[13];
  const float* b_Wq = (const float*)d_in[14];
  const float* b_bq = (const float*)d_in[15];
  const float* b_Wk = (const float*)d_in[16];
  const float* b_bk = (const float*)d_in[17];
  const float* b_Wv = (const float*)d_in[18];
  const float* b_bv = (const float*)d_in[19];
  const float* b_Wo = (const float*)d_in[20];
  const float* b_bo = (const float*)d_in[21];
  const float* W1   = (const float*)d_in[22];
  const float* b1   = (const float*)d_in[23];
  const float* ln2_g = (const float*)d_in[24];
  const float* ln2_b = (const float*)d_in[25];
  const float* W2   = (const float*)d_in[26];

  if (ws_size < 232314880) return;

  char* ws = (char*)d_ws;
  // wT slots: 0=W2t  [2+2i]=WqT_i [3+2i]=WkT_i(x0.125)  [10+i]=WvT_i  14..17=W1t
  __bf16* wT      = (__bf16*)(ws);
  __bf16* bWo_bf  = (__bf16*)(ws + 9437184);
  __bf16* Btbig   = (__bf16*)(ws + 11534336);
  float*  qkbias  = (float*)(ws + 13631488);
  float*  bias2   = (float*)(ws + 13647872);
  float*  kemo    = (float*)(ws + 13649920);
  float*  vemo    = (float*)(ws + 13664256);
  __bf16* Wqk_bf  = (__bf16*)(ws + 13678592);
  __bf16* VWo_bf  = (__bf16*)(ws + 13744128);
  float*  sbias   = (float*)(ws + 13809664);
  __bf16* htb     = (__bf16*)(ws + 13908224);
  __bf16* qkb2    = (__bf16*)(ws + 30685440);   // [16384][2048]
  __bf16* vtb_all = (__bf16*)(ws + 97794304);   // [2048][16384]
  __bf16* ctxa    = (__bf16*)(ws + 164903168);  // [16384][2048]
  // overlays
  __bf16* xb      = (__bf16*)(ws + 164903168);
  float*  partial = (float*)(ws + 30685440);
  float*  scores  = (float*)(ws + 30685440);
  __bf16* Pmat    = (__bf16*)(ws + 30685440 + 4194304);
  __bf16* sctx    = (__bf16*)(ws + 30685440 + 8388608);
  __bf16* tmpb    = qkb2;
  __bf16* heb     = (__bf16*)(ws + 47462656);

  // conversions + transposes
  cvt_f32_bf16_k<<<dim3(8192), 256, 0, stream>>>(x, xb);
  cvt_f32_bf16_k<<<dim3(1024), 256, 0, stream>>>(b_Wo, bWo_bf);
  {
    TP15 p;
    const float* srcs[13] = {b_Wq, b_Wq + SL, b_Wq + 2 * SL, b_Wq + 3 * SL,
                             b_Wk, b_Wk + SL, b_Wk + 2 * SL, b_Wk + 3 * SL,
                             b_Wv, b_Wv + SL, b_Wv + 2 * SL, b_Wv + 3 * SL,
                             W2};
    const int slots[13] = {2, 4, 6, 8, 3, 5, 7, 9, 10, 11, 12, 13, 0};
    for (int i = 0; i < 13; ++i) {
      p.src[i] = srcs[i]; p.slot[i] = slots[i];
      p.scl[i] = (i >= 4 && i < 8) ? 0.125f : 1.0f;
    }
    for (int i = 13; i < 15; ++i) { p.src[i] = W2; p.slot[i] = 0; p.scl[i] = 1.0f; }
    transpose_cvt15<<<dim3(16, 16, 13), 256, 0, stream>>>(p, wT);
  }
  transpose_cvt<<<dim3(16, 64), 256, 0, stream>>>(W1, wT + 14 * SL, 2048, 512);
  emo_kv<<<dim3(7, 2), 512, 0, stream>>>(emo, t_Wk, t_bk, t_Wv, t_bv, kemo, vemo);
  concat_qk_bias<<<dim3(4), 512, 0, stream>>>(b_bq, b_bk, qkbias);
  bias2_p1<<<dim3(16), 256, 0, stream>>>(b_bo, W1, partial);
  bias2_p2<<<dim3(2), 256, 0, stream>>>(b1, partial, bias2);
  sentprep<<<dim3(56), 512, 0, stream>>>(t_Wq, t_bq, t_Wo, kemo, vemo, Wqk_bf, VWo_bf, sbias);
  sentpad<<<dim3(8), 512, 0, stream>>>(Wqk_bf, sbias);
  gemm_bt64<true, 0, 0><<<dim3(8, 4, 4), 256, 0, stream>>>(wT + 14 * SL, bWo_bf, nullptr, Btbig,
                                                           512, 512, 2048, 2048, 512, SL, 512);

  // sentiment block on MFMA: scores -> softmax -> P@VWo -> LN
  gemm_bt64<false, 1, 0><<<dim3(1, 128), 256, 0, stream>>>(xb, Wqk_bf, sbias, scores,
                                                           64, 512, 512, 64, 0, 0, 0);
  softmax7<<<dim3(512), 256, 0, stream>>>(scores, Pmat);
  gemm_bt64<true, 1, 0><<<dim3(8, 128), 256, 0, stream>>>(Pmat, VWo_bf, t_bo, sctx,
                                                          512, 64, 64, 512, 0, 0, 0);
  ln1_bf<<<dim3(16384), 256, 0, stream>>>(sctx, x, t_ln_g, t_ln_b, htb);

  // merged V^T for all 4 branches (col-chunk swizzle: htb panel L2-local)
  gemm32<true, 2, 1><<<dim3(128, 8), 512, 0, stream>>>(wT + 10 * SL, htb, b_bv,
                                                       vtb_all, 16384, 512, 512, 16384);

  // two branch-pairs: merged qkproj (N=2048) + z-merged barrier-free attention
  for (int p = 0; p < 2; ++p) {
    gemm32<true, 1, 0><<<dim3(16, 64), 512, 0, stream>>>(htb, wT + (2 + 4 * p) * SL, qkbias + p * 2048,
                                                         qkb2, 2048, 512, 512, 2048);
    dim3 ag(512, 2);
    if (p == 0) attn_branch<0><<<ag, 256, 0, stream>>>(qkb2, vtb_all, ctxa, lengths, speakers);
    else        attn_branch<1><<<ag, 256, 0, stream>>>(qkb2, vtb_all, ctxa, lengths, speakers);
  }

  // fused (cat @ blockdiag(Wo) @ W1): K=2048
  gemm32<true, 1, 0><<<dim3(4, 64), 512, 0, stream>>>(ctxa, Btbig, bias2, tmpb, 512, 2048, 2048, 512);
  ln2_bb<<<dim3(16384), 256, 0, stream>>>(tmpb, htb, ln2_g, ln2_b, heb);
  gemm32<false, 0, 0><<<dim3(4, 64), 512, 0, stream>>>(heb, wT + 0 * SL, nullptr, (float*)d_out, 512, 512, 512, 512);
}

// Round 17
// 510.956 us; speedup vs baseline: 1.1283x; 1.1283x over previous
//
#include <hip/hip_runtime.h>

#define B_  64
#define T_  256
#define H_  512
#define NH_ 8
#define DH_ 64
#define M_  16384
#define SL  262144  // 512*512 elements per weight slot

typedef float  f32x4 __attribute__((ext_vector_type(4)));
typedef float  f32x2 __attribute__((ext_vector_type(2)));
typedef __bf16 b16x8 __attribute__((ext_vector_type(8)));
typedef __bf16 b16x4 __attribute__((ext_vector_type(4)));
typedef __bf16 b16x2 __attribute__((ext_vector_type(2)));

__device__ __forceinline__ void gload16(const void* g, void* l) {
  __builtin_amdgcn_global_load_lds((const __attribute__((address_space(1))) void*)g,
                                   (__attribute__((address_space(3))) void*)l, 16, 0, 0);
}

// ---------------- fp32 -> bf16 convert ----------------
__global__ __launch_bounds__(256) void cvt_f32_bf16_k(const float* __restrict__ in,
                                                      __bf16* __restrict__ out) {
  size_t i = ((size_t)blockIdx.x * 256 + threadIdx.x) * 4;
  f32x4 v = *(const f32x4*)(in + i);
  b16x4 o;
  o[0] = (__bf16)v[0]; o[1] = (__bf16)v[1]; o[2] = (__bf16)v[2]; o[3] = (__bf16)v[3];
  *(b16x4*)(out + i) = o;
}

// ---------------- batched weight transpose (+ optional scale): up to 15 slices ----------------
struct TP15 { const float* src[15]; int slot[15]; float scl[15]; };
__global__ __launch_bounds__(256) void transpose_cvt15(TP15 p, __bf16* __restrict__ wT) {
  __shared__ float tile[32][33];
  const float* in = p.src[blockIdx.z];
  __bf16* out = wT + (size_t)p.slot[blockIdx.z] * SL;
  const float scl = p.scl[blockIdx.z];
  int c0 = blockIdx.x * 32, r0 = blockIdx.y * 32;
  int tx = threadIdx.x & 31, ty = threadIdx.x >> 5;
  for (int yy = ty; yy < 32; yy += 8)
    tile[yy][tx] = in[(size_t)(r0 + yy) * 512 + c0 + tx];
  __syncthreads();
  for (int yy = ty; yy < 32; yy += 8)
    out[(size_t)(c0 + yy) * 512 + r0 + tx] = (__bf16)(tile[tx][yy] * scl);
}

// ---------------- generic transpose + convert (for W1: 2048x512) ----------------
__global__ __launch_bounds__(256) void transpose_cvt(const float* __restrict__ in,
                                                     __bf16* __restrict__ out, int R, int C) {
  __shared__ float tile[32][33];
  int c0 = blockIdx.x * 32, r0 = blockIdx.y * 32;
  int tx = threadIdx.x & 31, ty = threadIdx.x >> 5;
  for (int yy = ty; yy < 32; yy += 8)
    tile[yy][tx] = in[(size_t)(r0 + yy) * C + c0 + tx];
  __syncthreads();
  for (int yy = ty; yy < 32; yy += 8)
    out[(size_t)(c0 + yy) * R + r0 + tx] = (__bf16)tile[tx][yy];
}

// ---------------- emotion K/V: (7,512) = emo @ W + b ----------------
__global__ __launch_bounds__(512) void emo_kv(const float* __restrict__ emo,
                                              const float* __restrict__ Wk, const float* __restrict__ bk,
                                              const float* __restrict__ Wv, const float* __restrict__ bv,
                                              float* __restrict__ kout, float* __restrict__ vout) {
  int e = blockIdx.x, n = threadIdx.x;
  const float* W = blockIdx.y ? Wv : Wk;
  const float* bb = blockIdx.y ? bv : bk;
  float* o = blockIdx.y ? vout : kout;
  float acc = 0.f;
  for (int kk = 0; kk < 512; ++kk) acc += emo[e * 512 + kk] * W[kk * 512 + n];
  o[e * 512 + n] = acc + bb[n];
}

// ---------------- sentiment precompute (bf16, scale folded) ----------------
__global__ __launch_bounds__(512) void sentprep(const float* __restrict__ Wq,
                                                const float* __restrict__ bq,
                                                const float* __restrict__ Wo,
                                                const float* __restrict__ kemo,
                                                const float* __restrict__ vemo,
                                                __bf16* __restrict__ Wqk_bf,
                                                __bf16* __restrict__ VWo_bf,
                                                float* __restrict__ sbias) {
  const int he = blockIdx.x, h = he / 7, e = he % 7;
  const int t = threadIdx.x;
  const float* kp = kemo + e * 512 + h * 64;
  const float* wqr = Wq + (size_t)t * 512 + h * 64;
  float a = 0.f;
#pragma unroll 8
  for (int d = 0; d < 64; ++d) a += wqr[d] * kp[d];
  Wqk_bf[he * 512 + t] = (__bf16)(a * 0.125f);
  const float* vp = vemo + e * 512 + h * 64;
  float v = 0.f;
#pragma unroll 8
  for (int d = 0; d < 64; ++d) v += vp[d] * Wo[(size_t)(h * 64 + d) * 512 + t];
  VWo_bf[t * 64 + h * 8 + e] = (__bf16)v;
  if (e == 0) VWo_bf[t * 64 + h * 8 + 7] = (__bf16)0.f;
  if (t == 0) {
    float s = 0.f;
    for (int d = 0; d < 64; ++d) s += bq[h * 64 + d] * kp[d];
    sbias[he] = s * 0.125f;
  }
}

__global__ __launch_bounds__(512) void sentpad(__bf16* __restrict__ Wqk_bf,
                                               float* __restrict__ sbias) {
  int r = 56 + blockIdx.x;
  Wqk_bf[r * 512 + threadIdx.x] = (__bf16)0.f;
  if (threadIdx.x == 0) sbias[r] = 0.f;
}

// ---------------- bias helpers; pair layout [bq_{2p}, bk_{2p}*.125, bq_{2p+1}, bk_{2p+1}*.125] ----
__global__ __launch_bounds__(512) void concat_qk_bias(const float* __restrict__ bq,
                                                      const float* __restrict__ bk,
                                                      float* __restrict__ out) {
  int i = blockIdx.x, t = threadIdx.x;
  int base = (i >> 1) * 2048 + (i & 1) * 1024;
  out[base + t]       = bq[i * 512 + t];
  out[base + 512 + t] = bk[i * 512 + t] * 0.125f;
}

__global__ __launch_bounds__(256) void bias2_p1(const float* __restrict__ bo,
                                                const float* __restrict__ W1,
                                                float* __restrict__ partial) {
  int p = blockIdx.x, t = threadIdx.x;
  float a0 = 0.f, a1 = 0.f;
  for (int g = p * 128; g < p * 128 + 128; ++g) {
    float bg = bo[g];
    a0 += bg * W1[(size_t)g * 512 + t];
    a1 += bg * W1[(size_t)g * 512 + 256 + t];
  }
  partial[p * 512 + t] = a0;
  partial[p * 512 + 256 + t] = a1;
}

__global__ __launch_bounds__(256) void bias2_p2(const float* __restrict__ b1,
                                                const float* __restrict__ partial,
                                                float* __restrict__ out) {
  int o = blockIdx.x * 256 + threadIdx.x;
  float acc = b1[o];
#pragma unroll
  for (int p = 0; p < 16; ++p) acc += partial[p * 512 + o];
  out[o] = acc;
}

// ---------------- MFMA GEMM 256x128, 8 waves, BK=32, 2-phase, 48KB LDS ----
template<bool OB, int BM, int SW>
__global__ __launch_bounds__(512, 2) void gemm32(const __bf16* __restrict__ A,
                                                 const __bf16* __restrict__ Bt,
                                                 const float* __restrict__ bias,
                                                 void* __restrict__ Cv,
                                                 int N, int K, int lda, int ldc) {
  __shared__ __attribute__((aligned(16))) __bf16 As[2][256 * 32];
  __shared__ __attribute__((aligned(16))) __bf16 Bs[2][128 * 32];
  const int gx = gridDim.x;
  const int bid = blockIdx.y * gx + blockIdx.x;
  int bx, by;
  if (SW == 0) {
    const int nwg = gx * gridDim.y;
    const int cpx = nwg >> 3;
    const int swz = (bid & 7) * cpx + (bid >> 3);
    bx = swz % gx; by = swz / gx;
  } else {
    const int gxc = gx >> 3;
    const int u = bid >> 3, c = bid & 7;
    bx = c * gxc + u % gxc;
    by = u / gxc;
  }
  const int tid = threadIdx.x, lane = tid & 63, wid = tid >> 6;
  const int wr = wid >> 2, wc = wid & 3;
  const int m0 = by * 256, n0 = bx * 128;
  const int l15 = lane & 15, l16 = lane >> 4;
  const int ra = tid >> 2;
  const int xsl = (tid & 3) ^ ((ra >> 1) & 3);
  const int nt = K >> 5;
  f32x4 acc[8][2] = {};

#define STAGE32(buf, k0)                                                             \
  { char* aw = (char*)&As[buf][0];                                                   \
    char* bw = (char*)&Bs[buf][0];                                                   \
    gload16(A + (size_t)(m0 + ra) * lda + (k0) + xsl * 8, aw + tid * 16);            \
    gload16(A + (size_t)(m0 + 128 + ra) * lda + (k0) + xsl * 8, aw + (512 + tid) * 16); \
    gload16(Bt + (size_t)(n0 + ra) * K + (k0) + xsl * 8, bw + tid * 16); }

#define CMP32(buf)                                                                   \
  { const char* Ac = (const char*)&As[buf][0];                                       \
    const char* Bc = (const char*)&Bs[buf][0];                                       \
    const int swb = ((l16 ^ ((l15 >> 1) & 3)) << 4);                                 \
    b16x8 af[8], bf[2];                                                              \
    _Pragma("unroll")                                                                \
    for (int m = 0; m < 8; ++m)                                                      \
      af[m] = *(const b16x8*)(Ac + (wr * 128 + m * 16 + l15) * 64 + swb);            \
    _Pragma("unroll")                                                                \
    for (int n = 0; n < 2; ++n)                                                      \
      bf[n] = *(const b16x8*)(Bc + (wc * 32 + n * 16 + l15) * 64 + swb);             \
    __builtin_amdgcn_s_setprio(1);                                                   \
    _Pragma("unroll")                                                                \
    for (int m = 0; m < 8; ++m)                                                      \
      _Pragma("unroll")                                                              \
      for (int n = 0; n < 2; ++n)                                                    \
        acc[m][n] = __builtin_amdgcn_mfma_f32_16x16x32_bf16(af[m], bf[n], acc[m][n], 0, 0, 0); \
    __builtin_amdgcn_s_setprio(0); }

  STAGE32(0, 0);
  int cur = 0;
  for (int t = 0; t < nt; ++t) {
    if (t + 1 < nt) {
      STAGE32(cur ^ 1, (t + 1) * 32);
      asm volatile("s_waitcnt vmcnt(3)" ::: "memory");
    } else {
      asm volatile("s_waitcnt vmcnt(0)" ::: "memory");
    }
    __builtin_amdgcn_s_barrier();
    CMP32(cur);
    asm volatile("s_waitcnt lgkmcnt(0)" ::: "memory");
    __builtin_amdgcn_s_barrier();
    cur ^= 1;
  }
#undef STAGE32
#undef CMP32

  const int rb = m0 + wr * 128 + l16 * 4;
  const int cb = n0 + wc * 32 + l15;
#pragma unroll
  for (int n = 0; n < 2; ++n) {
    int gc = cb + n * 16;
    float bc = (BM == 1) ? bias[gc] : 0.0f;
#pragma unroll
    for (int m = 0; m < 8; ++m) {
#pragma unroll
      for (int rr = 0; rr < 4; ++rr) {
        int gr = rb + m * 16 + rr;
        float val = acc[m][n][rr] + ((BM == 2) ? bias[gr] : bc);
        if (OB) ((__bf16*)Cv)[(size_t)gr * ldc + gc] = (__bf16)val;
        else    ((float*)Cv)[(size_t)gr * ldc + gc] = val;
      }
    }
  }
}

// ---------------- MFMA GEMM 128x64 (proven; small/odd shapes, z-batched) ----------------
template<bool OB, int BM, int SW>
__global__ __launch_bounds__(256) void gemm_bt64(const __bf16* __restrict__ A,
                                                 const __bf16* __restrict__ Bt,
                                                 const float* __restrict__ bias,
                                                 void* __restrict__ Cv,
                                                 int N, int K, int lda, int ldc,
                                                 size_t zA, size_t zB, size_t zC) {
  __shared__ __attribute__((aligned(16))) __bf16 As[128 * 32];
  __shared__ __attribute__((aligned(16))) __bf16 Bs[64 * 32];
  A  += (size_t)blockIdx.z * zA;
  Bt += (size_t)blockIdx.z * zB;
  char* Cb = (char*)Cv + (size_t)blockIdx.z * zC * (OB ? 2 : 4);
  const int gx = gridDim.x;
  const int bid = blockIdx.y * gx + blockIdx.x;
  int bx, by;
  if (SW == 0) {
    const int nwg = gx * gridDim.y;
    const int cpx = nwg >> 3;
    const int swz = (bid & 7) * cpx + (bid >> 3);
    bx = swz % gx; by = swz / gx;
  } else {
    const int gxc = gx >> 3;
    const int u = bid >> 3, c = bid & 7;
    bx = c * gxc + u % gxc;
    by = u / gxc;
  }
  const int tid = threadIdx.x, lane = tid & 63, wid = tid >> 6;
  const int m0 = by * 128, n0 = bx * 64;
  const int l15 = lane & 15, l16 = lane >> 4;
  const int r0 = tid >> 2, o0 = (tid & 3) * 8;
  const __bf16* a0 = A + (size_t)(m0 + r0) * lda + o0;
  const __bf16* a1 = A + (size_t)(m0 + 64 + r0) * lda + o0;
  const __bf16* bp0 = Bt + (size_t)(n0 + r0) * K + o0;
  char* AsW = (char*)As + wid * 1024;
  char* BsW = (char*)Bs + wid * 1024;
  f32x4 acc[2][4] = {};
  for (int k0 = 0; k0 < K; k0 += 32) {
    gload16(a0 + k0, AsW);
    gload16(a1 + k0, AsW + 4096);
    gload16(bp0 + k0, BsW);
    __syncthreads();
    b16x8 af[2], bf[4];
#pragma unroll
    for (int m = 0; m < 2; ++m) af[m] = *(const b16x8*)&As[(wid * 32 + m * 16 + l15) * 32 + l16 * 8];
#pragma unroll
    for (int n = 0; n < 4; ++n) bf[n] = *(const b16x8*)&Bs[(n * 16 + l15) * 32 + l16 * 8];
#pragma unroll
    for (int m = 0; m < 2; ++m)
#pragma unroll
      for (int n = 0; n < 4; ++n)
        acc[m][n] = __builtin_amdgcn_mfma_f32_16x16x32_bf16(af[m], bf[n], acc[m][n], 0, 0, 0);
    __syncthreads();
  }
  const int rbase = m0 + wid * 32 + l16 * 4;
  const int cb = n0 + l15;
#pragma unroll
  for (int n = 0; n < 4; ++n) {
    int gc = cb + n * 16;
    float bc = (BM == 1) ? bias[gc] : 0.0f;
#pragma unroll
    for (int m = 0; m < 2; ++m) {
#pragma unroll
      for (int rr = 0; rr < 4; ++rr) {
        int gr = rbase + m * 16 + rr;
        float val = acc[m][n][rr] + ((BM == 2) ? bias[gr] : bc);
        if (OB) ((__bf16*)Cb)[(size_t)gr * ldc + gc] = (__bf16)val;
        else    ((float*)Cb)[(size_t)gr * ldc + gc] = val;
      }
    }
  }
}

// ---------------- per-(token,head) 7-wide softmax ----------------
__global__ __launch_bounds__(256) void softmax7(const float* __restrict__ scores,
                                                __bf16* __restrict__ P) {
  int idx = blockIdx.x * 256 + threadIdx.x;
  int m = idx >> 3, h = idx & 7;
  const float* s = scores + (size_t)m * 64 + h * 7;
  float v[7], mx = -3.4e38f;
#pragma unroll
  for (int e = 0; e < 7; ++e) { v[e] = s[e]; mx = fmaxf(mx, v[e]); }
  float sum = 0.f;
#pragma unroll
  for (int e = 0; e < 7; ++e) { v[e] = __expf(v[e] - mx); sum += v[e]; }
  float inv = 1.f / sum;
  __bf16* o = P + (size_t)m * 64 + h * 8;
#pragma unroll
  for (int e = 0; e < 7; ++e) o[e] = (__bf16)(v[e] * inv);
  o[7] = (__bf16)0.f;
}

// ---------------- bf16 pre + fp32 res LayerNorm -> bf16 ----------------
__global__ __launch_bounds__(256) void ln1_bf(const __bf16* __restrict__ pre,
                                              const float* __restrict__ res,
                                              const float* __restrict__ g,
                                              const float* __restrict__ bt,
                                              __bf16* __restrict__ ob) {
  int row = blockIdx.x, t = threadIdx.x;
  size_t base = (size_t)row * 512;
  b16x2 p2 = *(const b16x2*)(pre + base + 2 * t);
  f32x2 r2 = *(const f32x2*)(res + base + 2 * t);
  float v0 = (float)p2[0] + r2[0];
  float v1 = (float)p2[1] + r2[1];
  float s = v0 + v1, q = v0 * v0 + v1 * v1;
#pragma unroll
  for (int off = 32; off; off >>= 1) { s += __shfl_xor(s, off); q += __shfl_xor(q, off); }
  __shared__ float ls[4], lq[4];
  int wid = t >> 6, lane = t & 63;
  if (lane == 0) { ls[wid] = s; lq[wid] = q; }
  __syncthreads();
  s = ls[0] + ls[1] + ls[2] + ls[3];
  q = lq[0] + lq[1] + lq[2] + lq[3];
  float mean = s * (1.f / 512.f);
  float var = q * (1.f / 512.f) - mean * mean;
  float rstd = rsqrtf(fmaxf(var, 0.f) + 1e-12f);
  b16x2 o;
  o[0] = (__bf16)((v0 - mean) * rstd * g[2 * t] + bt[2 * t]);
  o[1] = (__bf16)((v1 - mean) * rstd * g[2 * t + 1] + bt[2 * t + 1]);
  *(b16x2*)(ob + base + 2 * t) = o;
}

// ---------------- bf16+bf16 residual LayerNorm ----------------
__global__ __launch_bounds__(256) void ln2_bb(const __bf16* __restrict__ pre,
                                              const __bf16* __restrict__ res,
                                              const float* __restrict__ g,
                                              const float* __restrict__ bt,
                                              __bf16* __restrict__ ob) {
  int row = blockIdx.x, t = threadIdx.x;
  size_t base = (size_t)row * 512;
  b16x2 p2 = *(const b16x2*)(pre + base + 2 * t);
  b16x2 r2 = *(const b16x2*)(res + base + 2 * t);
  float v0 = (float)p2[0] + (float)r2[0];
  float v1 = (float)p2[1] + (float)r2[1];
  float s = v0 + v1, q = v0 * v0 + v1 * v1;
#pragma unroll
  for (int off = 32; off; off >>= 1) { s += __shfl_xor(s, off); q += __shfl_xor(q, off); }
  __shared__ float ls[4], lq[4];
  int wid = t >> 6, lane = t & 63;
  if (lane == 0) { ls[wid] = s; lq[wid] = q; }
  __syncthreads();
  s = ls[0] + ls[1] + ls[2] + ls[3];
  q = lq[0] + lq[1] + lq[2] + lq[3];
  float mean = s * (1.f / 512.f);
  float var = q * (1.f / 512.f) - mean * mean;
  float rstd = rsqrtf(fmaxf(var, 0.f) + 1e-12f);
  b16x2 o;
  o[0] = (__bf16)((v0 - mean) * rstd * g[2 * t] + bt[2 * t]);
  o[1] = (__bf16)((v1 - mean) * rstd * g[2 * t + 1] + bt[2 * t + 1]);
  *(b16x2*)(ob + base + 2 * t) = o;
}

// ---------------- fused masked attention: K once, q-loop inside, FIXED-MAX softmax ----------------
// grid (bh=512, z=2); branch = PAIR*2 + z. Softmax uses row-uniform constant M* instead of
// computed max (shift-invariance): BR!=1 valid entries carry +C from mask-MFMA, M*=C+16;
// invalid ROWS get +C on all cols via 3rd bias channel (reduces to softmax(raw), matching the
// reference's cancelling -10000). BR==1 uses M*=16 with (ok||!rv) VALU mask.
template<int PAIR>
__global__ __launch_bounds__(256, 4) void attn_branch(const __bf16* __restrict__ qk,
                                                      const __bf16* __restrict__ vt,
                                                      __bf16* __restrict__ ctx,
                                                      const int* __restrict__ lengths,
                                                      const int* __restrict__ speakers) {
  __shared__ __attribute__((aligned(16))) __bf16 Ks[256 * 64];   // 32 KB, resident whole kernel
  __shared__ __attribute__((aligned(16))) __bf16 Ps[32 * 264];   // 16.5 KB P buffer
  __shared__ float redS[2][32];
  __shared__ int spk[256];
  const int sqk = 2048, so = 2048;
  const int tid = threadIdx.x, lane = tid & 63, wid = tid >> 6;
  const int l15 = lane & 15, l16 = lane >> 4;
  const int bh = blockIdx.x, z = blockIdx.y;
  const int BR = PAIR * 2 + z;
  const int b = bh >> 3, h = bh & 7;
  const int wq = wid & 1, wk = wid >> 1;
  const int mh = wid & 1, nh = wid >> 1;
  const __bf16* qp = qk + z * 1024;
  const __bf16* kp = qp + 512;
  const __bf16* vb2 = vt + (size_t)(BR * 512 + h * DH_) * M_ + b * T_;
  __bf16* ctxp = ctx + (size_t)BR * 512;
  const __bf16 CB = (__bf16)10000.0f, mCB = (__bf16)(-10000.0f), ZB = (__bf16)0.0f, OB1 = (__bf16)1.0f;
  const float CBF = (float)CB;                       // actual bf16-rounded C
  const float MSTAR = (BR == 1) ? 16.0f : CBF + 16.0f;

  {  // stage all 256 K rows once (xor-pre-swizzled source, linear LDS dest)
    const size_t kb0 = (size_t)(b * T_) * sqk + h * DH_;
    const int rsub = lane >> 3, slot = lane & 7;
#pragma unroll
    for (int j = 0; j < 8; ++j) {
      int row = (j * 4 + wid) * 8 + rsub;
      gload16(kp + kb0 + (size_t)row * sqk + ((slot ^ (row & 7)) * 8),
              (char*)Ks + (j * 4 + wid) * 1024);
    }
  }
  spk[tid] = speakers[b * T_ + tid];
  __syncthreads();   // K staged, spk visible
  const int L = lengths[b];

  // prefetch Q for qc=0
  b16x8 af0, af1;
  {
    const __bf16* qr = qp + (size_t)(b * T_ + wq * 16 + l15) * sqk + h * DH_;
    af0 = *(const b16x8*)(qr + l16 * 8);
    af1 = *(const b16x8*)(qr + 32 + l16 * 8);
  }

  for (int qc = 0; qc < 8; ++qc) {
    const int q0 = qc * 32;
    b16x8 afU = {};
    if (BR != 1 && l16 == 0) {
      int jA = q0 + wq * 16 + l15;
      bool rv = jA < L;
      afU[0] = rv ? OB1 : ZB;
      afU[1] = (rv && spk[jA]) ? OB1 : ZB;
      afU[2] = (BR == 0) ? OB1 : (rv ? ZB : OB1);   // BR0: all rows; BR2/3: invalid rows
    }

    f32x4 sa[4][2] = {};
#pragma unroll
    for (int kc = 0; kc < 4; ++kc) {
#pragma unroll
      for (int nn = 0; nn < 2; ++nn) {
        int krw = kc * 64 + wk * 32 + nn * 16 + l15;
        b16x8 b0 = *(const b16x8*)((char*)Ks + krw * 128 + ((l16 ^ (krw & 7)) * 16));
        sa[kc][nn] = __builtin_amdgcn_mfma_f32_16x16x32_bf16(af0, b0, sa[kc][nn], 0, 0, 0);
        b16x8 b1 = *(const b16x8*)((char*)Ks + krw * 128 + (((4 + l16) ^ (krw & 7)) * 16));
        sa[kc][nn] = __builtin_amdgcn_mfma_f32_16x16x32_bf16(af1, b1, sa[kc][nn], 0, 0, 0);
        if (BR != 1) {
          b16x8 w = {};
          if (l16 == 0) {
            bool cv = krw < L;
            int sc = spk[krw];
            if (BR == 0) {
              w[2] = cv ? CB : ZB;
            } else if (BR == 2) {
              w[0] = sc ? ZB : CB;
              w[1] = sc ? CB : mCB;
              w[2] = CB;
            } else {
              w[0] = (cv && sc) ? CB : ZB;
              w[1] = cv ? (sc ? mCB : CB) : ZB;
              w[2] = CB;
            }
          }
          sa[kc][nn] = __builtin_amdgcn_mfma_f32_16x16x32_bf16(afU, w, sa[kc][nn], 0, 0, 0);
        }
      }
    }

    // prefetch Q for qc+1 (hides under softmax+PV)
    if (qc + 1 < 8) {
      const __bf16* qr = qp + (size_t)(b * T_ + (qc + 1) * 32 + wq * 16 + l15) * sqk + h * DH_;
      af0 = *(const b16x8*)(qr + l16 * 8);
      af1 = *(const b16x8*)(qr + 32 + l16 * 8);
    }

    // fixed-max softmax: exp + row-sum only
    const int rloc = wq * 16 + l16 * 4;
    float sm[4];
#pragma unroll
    for (int rr = 0; rr < 4; ++rr) {
      const int j = q0 + rloc + rr;
      const bool rv = j < L;
      float s = 0.f;
#pragma unroll
      for (int kc = 0; kc < 4; ++kc)
#pragma unroll
        for (int nn = 0; nn < 2; ++nn) {
          float v = sa[kc][nn][rr];
          if (BR == 1) {
            int c = kc * 64 + wk * 32 + nn * 16 + l15;
            int dj = j - c;
            bool ok = (c < L) && (dj <= 2) && (dj >= -2);
            v += (ok || !rv) ? 0.0f : -10000.0f;
          }
          float e = __expf(v - MSTAR);
          sa[kc][nn][rr] = e;
          s += e;
        }
      s += __shfl_xor(s, 1); s += __shfl_xor(s, 2); s += __shfl_xor(s, 4); s += __shfl_xor(s, 8);
      sm[rr] = s;
    }
    // write P + partial sums, single barrier
#pragma unroll
    for (int rr = 0; rr < 4; ++rr) {
      if (l15 == 0) redS[wk][rloc + rr] = sm[rr];
#pragma unroll
      for (int kc = 0; kc < 4; ++kc)
#pragma unroll
        for (int nn = 0; nn < 2; ++nn)
          Ps[(rloc + rr) * 264 + kc * 64 + wk * 32 + nn * 16 + l15] = (__bf16)sa[kc][nn][rr];
    }
    __syncthreads();

    f32x4 oa[2] = {};
#pragma unroll
    for (int kt = 0; kt < 8; ++kt) {
      b16x8 afp = *(const b16x8*)(Ps + (mh * 16 + l15) * 264 + kt * 32 + l16 * 8);
#pragma unroll
      for (int n = 0; n < 2; ++n) {
        int d = nh * 32 + n * 16 + l15;
        b16x8 bfr = *(const b16x8*)(vb2 + (size_t)d * M_ + kt * 32 + l16 * 8);
        oa[n] = __builtin_amdgcn_mfma_f32_16x16x32_bf16(afp, bfr, oa[n], 0, 0, 0);
      }
    }
#pragma unroll
    for (int rr = 0; rr < 4; ++rr) {
      int row = mh * 16 + l16 * 4 + rr;
      float rinv = 1.0f / (redS[0][row] + redS[1][row]);
#pragma unroll
      for (int n = 0; n < 2; ++n)
        ctxp[(size_t)(b * T_ + q0 + row) * so + h * DH_ + nh * 32 + n * 16 + l15]
            = (__bf16)(oa[n][rr] * rinv);
    }
    __syncthreads();   // Ps/redS reads done before next-iter overwrite
  }
}

// ============================================================================
extern "C" void kernel_launch(void* const* d_in, const int* in_sizes, int n_in,
                              void* d_out, int out_size, void* d_ws, size_t ws_size,
                              hipStream_t stream) {
  const float* x        = (const float*)d_in[0];
  const int*   lengths  = (const int*)d_in[1];
  const int*   speakers = (const int*)d_in[2];
  const float* emo      = (const float*)d_in[3];
  const float* t_Wq = (const float*)d_in[4];
  const float* t_bq = (const float*)d_in[5];
  const float* t_Wk = (const float*)d_in[6];
  const float* t_bk = (const float*)d_in[7];
  const float* t_Wv = (const float*)d_in[8];
  const float* t_bv = (const float*)d_in[9];
  const float* t_Wo = (const float*)d_in[10];
  const float* t_bo = (const float*)d_in[11];
  const float* t_ln_g = (const float*)d_in[12];
  const float* t_ln_b = (const float*)d_in[13];
  const float* b_Wq = (const float*)d_in[14];
  const float* b_bq = (const float*)d_in[15];
  const float* b_Wk = (const float*)d_in[16];
  const float* b_bk = (const float*)d_in[17];
  const float* b_Wv = (const float*)d_in[18];
  const float* b_bv = (const float*)d_in[19];
  const float* b_Wo = (const float*)d_in[20];
  const float* b_bo = (const float*)d_in[21];
  const float* W1   = (const float*)d_in[22];
  const float* b1   = (const float*)d_in[23];
  const float* ln2_g = (const float*)d_in[24];
  const float* ln2_b = (const float*)d_in[25];
  const float* W2   = (const float*)d_in[26];

  if (ws_size < 232314880) return;

  char* ws = (char*)d_ws;
  // wT slots: 0=W2t  [2+2i]=WqT_i [3+2i]=WkT_i(x0.125)  [10+i]=WvT_i  14..17=W1t
  __bf16* wT      = (__bf16*)(ws);
  __bf16* bWo_bf  = (__bf16*)(ws + 9437184);
  __bf16* Btbig   = (__bf16*)(ws + 11534336);
  float*  qkbias  = (float*)(ws + 13631488);
  float*  bias2   = (float*)(ws + 13647872);
  float*  kemo    = (float*)(ws + 13649920);
  float*  vemo    = (float*)(ws + 13664256);
  __bf16* Wqk_bf  = (__bf16*)(ws + 13678592);
  __bf16* VWo_bf  = (__bf16*)(ws + 13744128);
  float*  sbias   = (float*)(ws + 13809664);
  __bf16* htb     = (__bf16*)(ws + 13908224);
  __bf16* qkb2    = (__bf16*)(ws + 30685440);   // [16384][2048]
  __bf16* vtb_all = (__bf16*)(ws + 97794304);   // [2048][16384]
  __bf16* ctxa    = (__bf16*)(ws + 164903168);  // [16384][2048]
  // overlays
  __bf16* xb      = (__bf16*)(ws + 164903168);
  float*  partial = (float*)(ws + 30685440);
  float*  scores  = (float*)(ws + 30685440);
  __bf16* Pmat    = (__bf16*)(ws + 30685440 + 4194304);
  __bf16* sctx    = (__bf16*)(ws + 30685440 + 8388608);
  __bf16* tmpb    = qkb2;
  __bf16* heb     = (__bf16*)(ws + 47462656);

  // conversions + transposes
  cvt_f32_bf16_k<<<dim3(8192), 256, 0, stream>>>(x, xb);
  cvt_f32_bf16_k<<<dim3(1024), 256, 0, stream>>>(b_Wo, bWo_bf);
  {
    TP15 p;
    const float* srcs[13] = {b_Wq, b_Wq + SL, b_Wq + 2 * SL, b_Wq + 3 * SL,
                             b_Wk, b_Wk + SL, b_Wk + 2 * SL, b_Wk + 3 * SL,
                             b_Wv, b_Wv + SL, b_Wv + 2 * SL, b_Wv + 3 * SL,
                             W2};
    const int slots[13] = {2, 4, 6, 8, 3, 5, 7, 9, 10, 11, 12, 13, 0};
    for (int i = 0; i < 13; ++i) {
      p.src[i] = srcs[i]; p.slot[i] = slots[i];
      p.scl[i] = (i >= 4 && i < 8) ? 0.125f : 1.0f;
    }
    for (int i = 13; i < 15; ++i) { p.src[i] = W2; p.slot[i] = 0; p.scl[i] = 1.0f; }
    transpose_cvt15<<<dim3(16, 16, 13), 256, 0, stream>>>(p, wT);
  }
  transpose_cvt<<<dim3(16, 64), 256, 0, stream>>>(W1, wT + 14 * SL, 2048, 512);
  emo_kv<<<dim3(7, 2), 512, 0, stream>>>(emo, t_Wk, t_bk, t_Wv, t_bv, kemo, vemo);
  concat_qk_bias<<<dim3(4), 512, 0, stream>>>(b_bq, b_bk, qkbias);
  bias2_p1<<<dim3(16), 256, 0, stream>>>(b_bo, W1, partial);
  bias2_p2<<<dim3(2), 256, 0, stream>>>(b1, partial, bias2);
  sentprep<<<dim3(56), 512, 0, stream>>>(t_Wq, t_bq, t_Wo, kemo, vemo, Wqk_bf, VWo_bf, sbias);
  sentpad<<<dim3(8), 512, 0, stream>>>(Wqk_bf, sbias);
  gemm_bt64<true, 0, 0><<<dim3(8, 4, 4), 256, 0, stream>>>(wT + 14 * SL, bWo_bf, nullptr, Btbig,
                                                           512, 512, 2048, 2048, 512, SL, 512);

  // sentiment block on MFMA: scores -> softmax -> P@VWo -> LN
  gemm_bt64<false, 1, 0><<<dim3(1, 128), 256, 0, stream>>>(xb, Wqk_bf, sbias, scores,
                                                           64, 512, 512, 64, 0, 0, 0);
  softmax7<<<dim3(512), 256, 0, stream>>>(scores, Pmat);
  gemm_bt64<true, 1, 0><<<dim3(8, 128), 256, 0, stream>>>(Pmat, VWo_bf, t_bo, sctx,
                                                          512, 64, 64, 512, 0, 0, 0);
  ln1_bf<<<dim3(16384), 256, 0, stream>>>(sctx, x, t_ln_g, t_ln_b, htb);

  // merged V^T for all 4 branches (col-chunk swizzle: htb panel L2-local)
  gemm32<true, 2, 1><<<dim3(128, 8), 512, 0, stream>>>(wT + 10 * SL, htb, b_bv,
                                                       vtb_all, 16384, 512, 512, 16384);

  // two branch-pairs: merged qkproj (N=2048) + z-merged attention with in-block q-loop
  for (int p = 0; p < 2; ++p) {
    gemm32<true, 1, 0><<<dim3(16, 64), 512, 0, stream>>>(htb, wT + (2 + 4 * p) * SL, qkbias + p * 2048,
                                                         qkb2, 2048, 512, 512, 2048);
    dim3 ag(512, 2);
    if (p == 0) attn_branch<0><<<ag, 256, 0, stream>>>(qkb2, vtb_all, ctxa, lengths, speakers);
    else        attn_branch<1><<<ag, 256, 0, stream>>>(qkb2, vtb_all, ctxa, lengths, speakers);
  }

  // fused (cat @ blockdiag(Wo) @ W1): K=2048
  gemm32<true, 1, 0><<<dim3(4, 64), 512, 0, stream>>>(ctxa, Btbig, bias2, tmpb, 512, 2048, 2048, 512);
  ln2_bb<<<dim3(16384), 256, 0, stream>>>(tmpb, htb, ln2_g, ln2_b, heb);
  gemm32<false, 0, 0><<<dim3(4, 64), 512, 0, stream>>>(heb, wT + 0 * SL, nullptr, (float*)d_out, 512, 512, 512, 512);
}

// Round 18
// 481.724 us; speedup vs baseline: 1.1968x; 1.0607x over previous
//
#include <hip/hip_runtime.h>

#define B_  64
#define T_  256
#define H_  512
#define NH_ 8
#define DH_ 64
#define M_  16384
#define SL  262144  // 512*512 elements per weight slot

typedef float  f32x4 __attribute__((ext_vector_type(4)));
typedef float  f32x2 __attribute__((ext_vector_type(2)));
typedef __bf16 b16x8 __attribute__((ext_vector_type(8)));
typedef __bf16 b16x4 __attribute__((ext_vector_type(4)));
typedef __bf16 b16x2 __attribute__((ext_vector_type(2)));

__device__ __forceinline__ void gload16(const void* g, void* l) {
  __builtin_amdgcn_global_load_lds((const __attribute__((address_space(1))) void*)g,
                                   (__attribute__((address_space(3))) void*)l, 16, 0, 0);
}

// ---------------- fp32 -> bf16 convert ----------------
__global__ __launch_bounds__(256) void cvt_f32_bf16_k(const float* __restrict__ in,
                                                      __bf16* __restrict__ out) {
  size_t i = ((size_t)blockIdx.x * 256 + threadIdx.x) * 4;
  f32x4 v = *(const f32x4*)(in + i);
  b16x4 o;
  o[0] = (__bf16)v[0]; o[1] = (__bf16)v[1]; o[2] = (__bf16)v[2]; o[3] = (__bf16)v[3];
  *(b16x4*)(out + i) = o;
}

// ---------------- batched weight transpose (+ optional scale): up to 15 slices ----------------
struct TP15 { const float* src[15]; int slot[15]; float scl[15]; };
__global__ __launch_bounds__(256) void transpose_cvt15(TP15 p, __bf16* __restrict__ wT) {
  __shared__ float tile[32][33];
  const float* in = p.src[blockIdx.z];
  __bf16* out = wT + (size_t)p.slot[blockIdx.z] * SL;
  const float scl = p.scl[blockIdx.z];
  int c0 = blockIdx.x * 32, r0 = blockIdx.y * 32;
  int tx = threadIdx.x & 31, ty = threadIdx.x >> 5;
  for (int yy = ty; yy < 32; yy += 8)
    tile[yy][tx] = in[(size_t)(r0 + yy) * 512 + c0 + tx];
  __syncthreads();
  for (int yy = ty; yy < 32; yy += 8)
    out[(size_t)(c0 + yy) * 512 + r0 + tx] = (__bf16)(tile[tx][yy] * scl);
}

// ---------------- generic transpose + convert (for W1: 2048x512) ----------------
__global__ __launch_bounds__(256) void transpose_cvt(const float* __restrict__ in,
                                                     __bf16* __restrict__ out, int R, int C) {
  __shared__ float tile[32][33];
  int c0 = blockIdx.x * 32, r0 = blockIdx.y * 32;
  int tx = threadIdx.x & 31, ty = threadIdx.x >> 5;
  for (int yy = ty; yy < 32; yy += 8)
    tile[yy][tx] = in[(size_t)(r0 + yy) * C + c0 + tx];
  __syncthreads();
  for (int yy = ty; yy < 32; yy += 8)
    out[(size_t)(c0 + yy) * R + r0 + tx] = (__bf16)tile[tx][yy];
}

// ---------------- emotion K/V: (7,512) = emo @ W + b ----------------
__global__ __launch_bounds__(512) void emo_kv(const float* __restrict__ emo,
                                              const float* __restrict__ Wk, const float* __restrict__ bk,
                                              const float* __restrict__ Wv, const float* __restrict__ bv,
                                              float* __restrict__ kout, float* __restrict__ vout) {
  int e = blockIdx.x, n = threadIdx.x;
  const float* W = blockIdx.y ? Wv : Wk;
  const float* bb = blockIdx.y ? bv : bk;
  float* o = blockIdx.y ? vout : kout;
  float acc = 0.f;
  for (int kk = 0; kk < 512; ++kk) acc += emo[e * 512 + kk] * W[kk * 512 + n];
  o[e * 512 + n] = acc + bb[n];
}

// ---------------- sentiment precompute (bf16, scale folded) ----------------
__global__ __launch_bounds__(512) void sentprep(const float* __restrict__ Wq,
                                                const float* __restrict__ bq,
                                                const float* __restrict__ Wo,
                                                const float* __restrict__ kemo,
                                                const float* __restrict__ vemo,
                                                __bf16* __restrict__ Wqk_bf,
                                                __bf16* __restrict__ VWo_bf,
                                                float* __restrict__ sbias) {
  const int he = blockIdx.x, h = he / 7, e = he % 7;
  const int t = threadIdx.x;
  const float* kp = kemo + e * 512 + h * 64;
  const float* wqr = Wq + (size_t)t * 512 + h * 64;
  float a = 0.f;
#pragma unroll 8
  for (int d = 0; d < 64; ++d) a += wqr[d] * kp[d];
  Wqk_bf[he * 512 + t] = (__bf16)(a * 0.125f);
  const float* vp = vemo + e * 512 + h * 64;
  float v = 0.f;
#pragma unroll 8
  for (int d = 0; d < 64; ++d) v += vp[d] * Wo[(size_t)(h * 64 + d) * 512 + t];
  VWo_bf[t * 64 + h * 8 + e] = (__bf16)v;
  if (e == 0) VWo_bf[t * 64 + h * 8 + 7] = (__bf16)0.f;
  if (t == 0) {
    float s = 0.f;
    for (int d = 0; d < 64; ++d) s += bq[h * 64 + d] * kp[d];
    sbias[he] = s * 0.125f;
  }
}

__global__ __launch_bounds__(512) void sentpad(__bf16* __restrict__ Wqk_bf,
                                               float* __restrict__ sbias) {
  int r = 56 + blockIdx.x;
  Wqk_bf[r * 512 + threadIdx.x] = (__bf16)0.f;
  if (threadIdx.x == 0) sbias[r] = 0.f;
}

// ---------------- bias helpers; pair layout [bq_{2p}, bk_{2p}*.125, bq_{2p+1}, bk_{2p+1}*.125] ----
__global__ __launch_bounds__(512) void concat_qk_bias(const float* __restrict__ bq,
                                                      const float* __restrict__ bk,
                                                      float* __restrict__ out) {
  int i = blockIdx.x, t = threadIdx.x;
  int base = (i >> 1) * 2048 + (i & 1) * 1024;
  out[base + t]       = bq[i * 512 + t];
  out[base + 512 + t] = bk[i * 512 + t] * 0.125f;
}

__global__ __launch_bounds__(256) void bias2_p1(const float* __restrict__ bo,
                                                const float* __restrict__ W1,
                                                float* __restrict__ partial) {
  int p = blockIdx.x, t = threadIdx.x;
  float a0 = 0.f, a1 = 0.f;
  for (int g = p * 128; g < p * 128 + 128; ++g) {
    float bg = bo[g];
    a0 += bg * W1[(size_t)g * 512 + t];
    a1 += bg * W1[(size_t)g * 512 + 256 + t];
  }
  partial[p * 512 + t] = a0;
  partial[p * 512 + 256 + t] = a1;
}

__global__ __launch_bounds__(256) void bias2_p2(const float* __restrict__ b1,
                                                const float* __restrict__ partial,
                                                float* __restrict__ out) {
  int o = blockIdx.x * 256 + threadIdx.x;
  float acc = b1[o];
#pragma unroll
  for (int p = 0; p < 16; ++p) acc += partial[p * 512 + o];
  out[o] = acc;
}

// ---------------- MFMA GEMM 256x128, 8 waves, BK=32, 2-phase, 48KB LDS ----
// bf16 output path: LDS-transposed coalesced epilogue (1x global_store_dwordx4 per m-tile)
template<bool OB, int BM, int SW>
__global__ __launch_bounds__(512, 2) void gemm32(const __bf16* __restrict__ A,
                                                 const __bf16* __restrict__ Bt,
                                                 const float* __restrict__ bias,
                                                 void* __restrict__ Cv,
                                                 int N, int K, int lda, int ldc) {
  __shared__ __attribute__((aligned(16))) __bf16 As[2][256 * 32];
  __shared__ __attribute__((aligned(16))) __bf16 Bs[2][128 * 32];
  const int gx = gridDim.x;
  const int bid = blockIdx.y * gx + blockIdx.x;
  int bx, by;
  if (SW == 0) {
    const int nwg = gx * gridDim.y;
    const int cpx = nwg >> 3;
    const int swz = (bid & 7) * cpx + (bid >> 3);
    bx = swz % gx; by = swz / gx;
  } else {
    const int gxc = gx >> 3;
    const int u = bid >> 3, c = bid & 7;
    bx = c * gxc + u % gxc;
    by = u / gxc;
  }
  const int tid = threadIdx.x, lane = tid & 63, wid = tid >> 6;
  const int wr = wid >> 2, wc = wid & 3;
  const int m0 = by * 256, n0 = bx * 128;
  const int l15 = lane & 15, l16 = lane >> 4;
  const int ra = tid >> 2;
  const int xsl = (tid & 3) ^ ((ra >> 1) & 3);
  const int nt = K >> 5;
  f32x4 acc[8][2] = {};

#define STAGE32(buf, k0)                                                             \
  { char* aw = (char*)&As[buf][0];                                                   \
    char* bw = (char*)&Bs[buf][0];                                                   \
    gload16(A + (size_t)(m0 + ra) * lda + (k0) + xsl * 8, aw + tid * 16);            \
    gload16(A + (size_t)(m0 + 128 + ra) * lda + (k0) + xsl * 8, aw + (512 + tid) * 16); \
    gload16(Bt + (size_t)(n0 + ra) * K + (k0) + xsl * 8, bw + tid * 16); }

#define CMP32(buf)                                                                   \
  { const char* Ac = (const char*)&As[buf][0];                                       \
    const char* Bc = (const char*)&Bs[buf][0];                                       \
    const int swb = ((l16 ^ ((l15 >> 1) & 3)) << 4);                                 \
    b16x8 af[8], bf[2];                                                              \
    _Pragma("unroll")                                                                \
    for (int m = 0; m < 8; ++m)                                                      \
      af[m] = *(const b16x8*)(Ac + (wr * 128 + m * 16 + l15) * 64 + swb);            \
    _Pragma("unroll")                                                                \
    for (int n = 0; n < 2; ++n)                                                      \
      bf[n] = *(const b16x8*)(Bc + (wc * 32 + n * 16 + l15) * 64 + swb);             \
    __builtin_amdgcn_s_setprio(1);                                                   \
    _Pragma("unroll")                                                                \
    for (int m = 0; m < 8; ++m)                                                      \
      _Pragma("unroll")                                                              \
      for (int n = 0; n < 2; ++n)                                                    \
        acc[m][n] = __builtin_amdgcn_mfma_f32_16x16x32_bf16(af[m], bf[n], acc[m][n], 0, 0, 0); \
    __builtin_amdgcn_s_setprio(0); }

  STAGE32(0, 0);
  int cur = 0;
  for (int t = 0; t < nt; ++t) {
    if (t + 1 < nt) {
      STAGE32(cur ^ 1, (t + 1) * 32);
      asm volatile("s_waitcnt vmcnt(3)" ::: "memory");
    } else {
      asm volatile("s_waitcnt vmcnt(0)" ::: "memory");
    }
    __builtin_amdgcn_s_barrier();
    CMP32(cur);
    asm volatile("s_waitcnt lgkmcnt(0)" ::: "memory");
    __builtin_amdgcn_s_barrier();
    cur ^= 1;
  }
#undef STAGE32
#undef CMP32

  const int rb = m0 + wr * 128 + l16 * 4;
  const int cb = n0 + wc * 32 + l15;
  if constexpr (OB) {
    // coalesced epilogue: wave-private LDS transpose strip in dead As region.
    // layout: [16 rows][pad 40 bf16] -> 80B row stride (16B-aligned), ~2-way banks.
    __bf16* tb = (__bf16*)((char*)&As[0][0] + wid * 2048);
    const int strow = lane >> 2, sseg = (lane & 3) * 8;
#pragma unroll
    for (int m = 0; m < 8; ++m) {
#pragma unroll
      for (int n = 0; n < 2; ++n) {
        float bc = (BM == 1) ? bias[cb + n * 16] : 0.0f;
#pragma unroll
        for (int rr = 0; rr < 4; ++rr) {
          float val = acc[m][n][rr] + ((BM == 2) ? bias[rb + m * 16 + rr] : bc);
          tb[(l16 * 4 + rr) * 40 + n * 16 + l15] = (__bf16)val;
        }
      }
      asm volatile("s_waitcnt lgkmcnt(0)" ::: "memory");   // writes visible wave-wide
      b16x8 v = *(const b16x8*)&tb[strow * 40 + sseg];
      *(b16x8*)((__bf16*)Cv + (size_t)(m0 + wr * 128 + m * 16 + strow) * ldc
                + n0 + wc * 32 + sseg) = v;
      asm volatile("s_waitcnt lgkmcnt(0)" ::: "memory");   // reads done before next-m overwrite
    }
  } else {
#pragma unroll
    for (int n = 0; n < 2; ++n) {
      int gc = cb + n * 16;
      float bc = (BM == 1) ? bias[gc] : 0.0f;
#pragma unroll
      for (int m = 0; m < 8; ++m) {
#pragma unroll
        for (int rr = 0; rr < 4; ++rr) {
          int gr = rb + m * 16 + rr;
          float val = acc[m][n][rr] + ((BM == 2) ? bias[gr] : bc);
          ((float*)Cv)[(size_t)gr * ldc + gc] = val;
        }
      }
    }
  }
}

// ---------------- MFMA GEMM 128x64 (proven; small/odd shapes, z-batched) ----------------
template<bool OB, int BM, int SW>
__global__ __launch_bounds__(256) void gemm_bt64(const __bf16* __restrict__ A,
                                                 const __bf16* __restrict__ Bt,
                                                 const float* __restrict__ bias,
                                                 void* __restrict__ Cv,
                                                 int N, int K, int lda, int ldc,
                                                 size_t zA, size_t zB, size_t zC) {
  __shared__ __attribute__((aligned(16))) __bf16 As[128 * 32];
  __shared__ __attribute__((aligned(16))) __bf16 Bs[64 * 32];
  A  += (size_t)blockIdx.z * zA;
  Bt += (size_t)blockIdx.z * zB;
  char* Cb = (char*)Cv + (size_t)blockIdx.z * zC * (OB ? 2 : 4);
  const int gx = gridDim.x;
  const int bid = blockIdx.y * gx + blockIdx.x;
  int bx, by;
  if (SW == 0) {
    const int nwg = gx * gridDim.y;
    const int cpx = nwg >> 3;
    const int swz = (bid & 7) * cpx + (bid >> 3);
    bx = swz % gx; by = swz / gx;
  } else {
    const int gxc = gx >> 3;
    const int u = bid >> 3, c = bid & 7;
    bx = c * gxc + u % gxc;
    by = u / gxc;
  }
  const int tid = threadIdx.x, lane = tid & 63, wid = tid >> 6;
  const int m0 = by * 128, n0 = bx * 64;
  const int l15 = lane & 15, l16 = lane >> 4;
  const int r0 = tid >> 2, o0 = (tid & 3) * 8;
  const __bf16* a0 = A + (size_t)(m0 + r0) * lda + o0;
  const __bf16* a1 = A + (size_t)(m0 + 64 + r0) * lda + o0;
  const __bf16* bp0 = Bt + (size_t)(n0 + r0) * K + o0;
  char* AsW = (char*)As + wid * 1024;
  char* BsW = (char*)Bs + wid * 1024;
  f32x4 acc[2][4] = {};
  for (int k0 = 0; k0 < K; k0 += 32) {
    gload16(a0 + k0, AsW);
    gload16(a1 + k0, AsW + 4096);
    gload16(bp0 + k0, BsW);
    __syncthreads();
    b16x8 af[2], bf[4];
#pragma unroll
    for (int m = 0; m < 2; ++m) af[m] = *(const b16x8*)&As[(wid * 32 + m * 16 + l15) * 32 + l16 * 8];
#pragma unroll
    for (int n = 0; n < 4; ++n) bf[n] = *(const b16x8*)&Bs[(n * 16 + l15) * 32 + l16 * 8];
#pragma unroll
    for (int m = 0; m < 2; ++m)
#pragma unroll
      for (int n = 0; n < 4; ++n)
        acc[m][n] = __builtin_amdgcn_mfma_f32_16x16x32_bf16(af[m], bf[n], acc[m][n], 0, 0, 0);
    __syncthreads();
  }
  const int rbase = m0 + wid * 32 + l16 * 4;
  const int cb = n0 + l15;
#pragma unroll
  for (int n = 0; n < 4; ++n) {
    int gc = cb + n * 16;
    float bc = (BM == 1) ? bias[gc] : 0.0f;
#pragma unroll
    for (int m = 0; m < 2; ++m) {
#pragma unroll
      for (int rr = 0; rr < 4; ++rr) {
        int gr = rbase + m * 16 + rr;
        float val = acc[m][n][rr] + ((BM == 2) ? bias[gr] : bc);
        if (OB) ((__bf16*)Cb)[(size_t)gr * ldc + gc] = (__bf16)val;
        else    ((float*)Cb)[(size_t)gr * ldc + gc] = val;
      }
    }
  }
}

// ---------------- per-(token,head) 7-wide softmax ----------------
__global__ __launch_bounds__(256) void softmax7(const float* __restrict__ scores,
                                                __bf16* __restrict__ P) {
  int idx = blockIdx.x * 256 + threadIdx.x;
  int m = idx >> 3, h = idx & 7;
  const float* s = scores + (size_t)m * 64 + h * 7;
  float v[7], mx = -3.4e38f;
#pragma unroll
  for (int e = 0; e < 7; ++e) { v[e] = s[e]; mx = fmaxf(mx, v[e]); }
  float sum = 0.f;
#pragma unroll
  for (int e = 0; e < 7; ++e) { v[e] = __expf(v[e] - mx); sum += v[e]; }
  float inv = 1.f / sum;
  __bf16* o = P + (size_t)m * 64 + h * 8;
#pragma unroll
  for (int e = 0; e < 7; ++e) o[e] = (__bf16)(v[e] * inv);
  o[7] = (__bf16)0.f;
}

// ---------------- bf16 pre + fp32 res LayerNorm -> bf16 ----------------
__global__ __launch_bounds__(256) void ln1_bf(const __bf16* __restrict__ pre,
                                              const float* __restrict__ res,
                                              const float* __restrict__ g,
                                              const float* __restrict__ bt,
                                              __bf16* __restrict__ ob) {
  int row = blockIdx.x, t = threadIdx.x;
  size_t base = (size_t)row * 512;
  b16x2 p2 = *(const b16x2*)(pre + base + 2 * t);
  f32x2 r2 = *(const f32x2*)(res + base + 2 * t);
  float v0 = (float)p2[0] + r2[0];
  float v1 = (float)p2[1] + r2[1];
  float s = v0 + v1, q = v0 * v0 + v1 * v1;
#pragma unroll
  for (int off = 32; off; off >>= 1) { s += __shfl_xor(s, off); q += __shfl_xor(q, off); }
  __shared__ float ls[4], lq[4];
  int wid = t >> 6, lane = t & 63;
  if (lane == 0) { ls[wid] = s; lq[wid] = q; }
  __syncthreads();
  s = ls[0] + ls[1] + ls[2] + ls[3];
  q = lq[0] + lq[1] + lq[2] + lq[3];
  float mean = s * (1.f / 512.f);
  float var = q * (1.f / 512.f) - mean * mean;
  float rstd = rsqrtf(fmaxf(var, 0.f) + 1e-12f);
  b16x2 o;
  o[0] = (__bf16)((v0 - mean) * rstd * g[2 * t] + bt[2 * t]);
  o[1] = (__bf16)((v1 - mean) * rstd * g[2 * t + 1] + bt[2 * t + 1]);
  *(b16x2*)(ob + base + 2 * t) = o;
}

// ---------------- bf16+bf16 residual LayerNorm ----------------
__global__ __launch_bounds__(256) void ln2_bb(const __bf16* __restrict__ pre,
                                              const __bf16* __restrict__ res,
                                              const float* __restrict__ g,
                                              const float* __restrict__ bt,
                                              __bf16* __restrict__ ob) {
  int row = blockIdx.x, t = threadIdx.x;
  size_t base = (size_t)row * 512;
  b16x2 p2 = *(const b16x2*)(pre + base + 2 * t);
  b16x2 r2 = *(const b16x2*)(res + base + 2 * t);
  float v0 = (float)p2[0] + (float)r2[0];
  float v1 = (float)p2[1] + (float)r2[1];
  float s = v0 + v1, q = v0 * v0 + v1 * v1;
#pragma unroll
  for (int off = 32; off; off >>= 1) { s += __shfl_xor(s, off); q += __shfl_xor(q, off); }
  __shared__ float ls[4], lq[4];
  int wid = t >> 6, lane = t & 63;
  if (lane == 0) { ls[wid] = s; lq[wid] = q; }
  __syncthreads();
  s = ls[0] + ls[1] + ls[2] + ls[3];
  q = lq[0] + lq[1] + lq[2] + lq[3];
  float mean = s * (1.f / 512.f);
  float var = q * (1.f / 512.f) - mean * mean;
  float rstd = rsqrtf(fmaxf(var, 0.f) + 1e-12f);
  b16x2 o;
  o[0] = (__bf16)((v0 - mean) * rstd * g[2 * t] + bt[2 * t]);
  o[1] = (__bf16)((v1 - mean) * rstd * g[2 * t + 1] + bt[2 * t + 1]);
  *(b16x2*)(ob + base + 2 * t) = o;
}

// ---------------- fused masked attention: K once, q-loop inside, FIXED-MAX softmax ----------------
template<int PAIR>
__global__ __launch_bounds__(256, 4) void attn_branch(const __bf16* __restrict__ qk,
                                                      const __bf16* __restrict__ vt,
                                                      __bf16* __restrict__ ctx,
                                                      const int* __restrict__ lengths,
                                                      const int* __restrict__ speakers) {
  __shared__ __attribute__((aligned(16))) __bf16 Ks[256 * 64];
  __shared__ __attribute__((aligned(16))) __bf16 Ps[32 * 264];
  __shared__ float redS[2][32];
  __shared__ int spk[256];
  const int sqk = 2048, so = 2048;
  const int tid = threadIdx.x, lane = tid & 63, wid = tid >> 6;
  const int l15 = lane & 15, l16 = lane >> 4;
  const int bh = blockIdx.x, z = blockIdx.y;
  const int BR = PAIR * 2 + z;
  const int b = bh >> 3, h = bh & 7;
  const int wq = wid & 1, wk = wid >> 1;
  const int mh = wid & 1, nh = wid >> 1;
  const __bf16* qp = qk + z * 1024;
  const __bf16* kp = qp + 512;
  const __bf16* vb2 = vt + (size_t)(BR * 512 + h * DH_) * M_ + b * T_;
  __bf16* ctxp = ctx + (size_t)BR * 512;
  const __bf16 CB = (__bf16)10000.0f, mCB = (__bf16)(-10000.0f), ZB = (__bf16)0.0f, OB1 = (__bf16)1.0f;
  const float CBF = (float)CB;
  const float MSTAR = (BR == 1) ? 16.0f : CBF + 16.0f;

  {
    const size_t kb0 = (size_t)(b * T_) * sqk + h * DH_;
    const int rsub = lane >> 3, slot = lane & 7;
#pragma unroll
    for (int j = 0; j < 8; ++j) {
      int row = (j * 4 + wid) * 8 + rsub;
      gload16(kp + kb0 + (size_t)row * sqk + ((slot ^ (row & 7)) * 8),
              (char*)Ks + (j * 4 + wid) * 1024);
    }
  }
  spk[tid] = speakers[b * T_ + tid];
  __syncthreads();
  const int L = lengths[b];

  b16x8 af0, af1;
  {
    const __bf16* qr = qp + (size_t)(b * T_ + wq * 16 + l15) * sqk + h * DH_;
    af0 = *(const b16x8*)(qr + l16 * 8);
    af1 = *(const b16x8*)(qr + 32 + l16 * 8);
  }

  for (int qc = 0; qc < 8; ++qc) {
    const int q0 = qc * 32;
    b16x8 afU = {};
    if (BR != 1 && l16 == 0) {
      int jA = q0 + wq * 16 + l15;
      bool rv = jA < L;
      afU[0] = rv ? OB1 : ZB;
      afU[1] = (rv && spk[jA]) ? OB1 : ZB;
      afU[2] = (BR == 0) ? OB1 : (rv ? ZB : OB1);
    }

    f32x4 sa[4][2] = {};
#pragma unroll
    for (int kc = 0; kc < 4; ++kc) {
#pragma unroll
      for (int nn = 0; nn < 2; ++nn) {
        int krw = kc * 64 + wk * 32 + nn * 16 + l15;
        b16x8 b0 = *(const b16x8*)((char*)Ks + krw * 128 + ((l16 ^ (krw & 7)) * 16));
        sa[kc][nn] = __builtin_amdgcn_mfma_f32_16x16x32_bf16(af0, b0, sa[kc][nn], 0, 0, 0);
        b16x8 b1 = *(const b16x8*)((char*)Ks + krw * 128 + (((4 + l16) ^ (krw & 7)) * 16));
        sa[kc][nn] = __builtin_amdgcn_mfma_f32_16x16x32_bf16(af1, b1, sa[kc][nn], 0, 0, 0);
        if (BR != 1) {
          b16x8 w = {};
          if (l16 == 0) {
            bool cv = krw < L;
            int sc = spk[krw];
            if (BR == 0) {
              w[2] = cv ? CB : ZB;
            } else if (BR == 2) {
              w[0] = sc ? ZB : CB;
              w[1] = sc ? CB : mCB;
              w[2] = CB;
            } else {
              w[0] = (cv && sc) ? CB : ZB;
              w[1] = cv ? (sc ? mCB : CB) : ZB;
              w[2] = CB;
            }
          }
          sa[kc][nn] = __builtin_amdgcn_mfma_f32_16x16x32_bf16(afU, w, sa[kc][nn], 0, 0, 0);
        }
      }
    }

    if (qc + 1 < 8) {
      const __bf16* qr = qp + (size_t)(b * T_ + (qc + 1) * 32 + wq * 16 + l15) * sqk + h * DH_;
      af0 = *(const b16x8*)(qr + l16 * 8);
      af1 = *(const b16x8*)(qr + 32 + l16 * 8);
    }

    const int rloc = wq * 16 + l16 * 4;
    float sm[4];
#pragma unroll
    for (int rr = 0; rr < 4; ++rr) {
      const int j = q0 + rloc + rr;
      const bool rv = j < L;
      float s = 0.f;
#pragma unroll
      for (int kc = 0; kc < 4; ++kc)
#pragma unroll
        for (int nn = 0; nn < 2; ++nn) {
          float v = sa[kc][nn][rr];
          if (BR == 1) {
            int c = kc * 64 + wk * 32 + nn * 16 + l15;
            int dj = j - c;
            bool ok = (c < L) && (dj <= 2) && (dj >= -2);
            v += (ok || !rv) ? 0.0f : -10000.0f;
          }
          float e = __expf(v - MSTAR);
          sa[kc][nn][rr] = e;
          s += e;
        }
      s += __shfl_xor(s, 1); s += __shfl_xor(s, 2); s += __shfl_xor(s, 4); s += __shfl_xor(s, 8);
      sm[rr] = s;
    }
#pragma unroll
    for (int rr = 0; rr < 4; ++rr) {
      if (l15 == 0) redS[wk][rloc + rr] = sm[rr];
#pragma unroll
      for (int kc = 0; kc < 4; ++kc)
#pragma unroll
        for (int nn = 0; nn < 2; ++nn)
          Ps[(rloc + rr) * 264 + kc * 64 + wk * 32 + nn * 16 + l15] = (__bf16)sa[kc][nn][rr];
    }
    __syncthreads();

    f32x4 oa[2] = {};
#pragma unroll
    for (int kt = 0; kt < 8; ++kt) {
      b16x8 afp = *(const b16x8*)(Ps + (mh * 16 + l15) * 264 + kt * 32 + l16 * 8);
#pragma unroll
      for (int n = 0; n < 2; ++n) {
        int d = nh * 32 + n * 16 + l15;
        b16x8 bfr = *(const b16x8*)(vb2 + (size_t)d * M_ + kt * 32 + l16 * 8);
        oa[n] = __builtin_amdgcn_mfma_f32_16x16x32_bf16(afp, bfr, oa[n], 0, 0, 0);
      }
    }
#pragma unroll
    for (int rr = 0; rr < 4; ++rr) {
      int row = mh * 16 + l16 * 4 + rr;
      float rinv = 1.0f / (redS[0][row] + redS[1][row]);
#pragma unroll
      for (int n = 0; n < 2; ++n)
        ctxp[(size_t)(b * T_ + q0 + row) * so + h * DH_ + nh * 32 + n * 16 + l15]
            = (__bf16)(oa[n][rr] * rinv);
    }
    __syncthreads();
  }
}

// ============================================================================
extern "C" void kernel_launch(void* const* d_in, const int* in_sizes, int n_in,
                              void* d_out, int out_size, void* d_ws, size_t ws_size,
                              hipStream_t stream) {
  const float* x        = (const float*)d_in[0];
  const int*   lengths  = (const int*)d_in[1];
  const int*   speakers = (const int*)d_in[2];
  const float* emo      = (const float*)d_in[3];
  const float* t_Wq = (const float*)d_in[4];
  const float* t_bq = (const float*)d_in[5];
  const float* t_Wk = (const float*)d_in[6];
  const float* t_bk = (const float*)d_in[7];
  const float* t_Wv = (const float*)d_in[8];
  const float* t_bv = (const float*)d_in[9];
  const float* t_Wo = (const float*)d_in[10];
  const float* t_bo = (const float*)d_in[11];
  const float* t_ln_g = (const float*)d_in[12];
  const float* t_ln_b = (const float*)d_in[13];
  const float* b_Wq = (const float*)d_in[14];
  const float* b_bq = (const float*)d_in[15];
  const float* b_Wk = (const float*)d_in[16];
  const float* b_bk = (const float*)d_in[17];
  const float* b_Wv = (const float*)d_in[18];
  const float* b_bv = (const float*)d_in[19];
  const float* b_Wo = (const float*)d_in[20];
  const float* b_bo = (const float*)d_in[21];
  const float* W1   = (const float*)d_in[22];
  const float* b1   = (const float*)d_in[23];
  const float* ln2_g = (const float*)d_in[24];
  const float* ln2_b = (const float*)d_in[25];
  const float* W2   = (const float*)d_in[26];

  if (ws_size < 232314880) return;

  char* ws = (char*)d_ws;
  // wT slots: 0=W2t  [2+2i]=WqT_i [3+2i]=WkT_i(x0.125)  [10+i]=WvT_i  14..17=W1t
  __bf16* wT      = (__bf16*)(ws);
  __bf16* bWo_bf  = (__bf16*)(ws + 9437184);
  __bf16* Btbig   = (__bf16*)(ws + 11534336);
  float*  qkbias  = (float*)(ws + 13631488);
  float*  bias2   = (float*)(ws + 13647872);
  float*  kemo    = (float*)(ws + 13649920);
  float*  vemo    = (float*)(ws + 13664256);
  __bf16* Wqk_bf  = (__bf16*)(ws + 13678592);
  __bf16* VWo_bf  = (__bf16*)(ws + 13744128);
  float*  sbias   = (float*)(ws + 13809664);
  __bf16* htb     = (__bf16*)(ws + 13908224);
  __bf16* qkb2    = (__bf16*)(ws + 30685440);   // [16384][2048]
  __bf16* vtb_all = (__bf16*)(ws + 97794304);   // [2048][16384]
  __bf16* ctxa    = (__bf16*)(ws + 164903168);  // [16384][2048]
  // overlays
  __bf16* xb      = (__bf16*)(ws + 164903168);
  float*  partial = (float*)(ws + 30685440);
  float*  scores  = (float*)(ws + 30685440);
  __bf16* Pmat    = (__bf16*)(ws + 30685440 + 4194304);
  __bf16* sctx    = (__bf16*)(ws + 30685440 + 8388608);
  __bf16* tmpb    = qkb2;
  __bf16* heb     = (__bf16*)(ws + 47462656);

  // conversions + transposes
  cvt_f32_bf16_k<<<dim3(8192), 256, 0, stream>>>(x, xb);
  cvt_f32_bf16_k<<<dim3(1024), 256, 0, stream>>>(b_Wo, bWo_bf);
  {
    TP15 p;
    const float* srcs[13] = {b_Wq, b_Wq + SL, b_Wq + 2 * SL, b_Wq + 3 * SL,
                             b_Wk, b_Wk + SL, b_Wk + 2 * SL, b_Wk + 3 * SL,
                             b_Wv, b_Wv + SL, b_Wv + 2 * SL, b_Wv + 3 * SL,
                             W2};
    const int slots[13] = {2, 4, 6, 8, 3, 5, 7, 9, 10, 11, 12, 13, 0};
    for (int i = 0; i < 13; ++i) {
      p.src[i] = srcs[i]; p.slot[i] = slots[i];
      p.scl[i] = (i >= 4 && i < 8) ? 0.125f : 1.0f;
    }
    for (int i = 13; i < 15; ++i) { p.src[i] = W2; p.slot[i] = 0; p.scl[i] = 1.0f; }
    transpose_cvt15<<<dim3(16, 16, 13), 256, 0, stream>>>(p, wT);
  }
  transpose_cvt<<<dim3(16, 64), 256, 0, stream>>>(W1, wT + 14 * SL, 2048, 512);
  emo_kv<<<dim3(7, 2), 512, 0, stream>>>(emo, t_Wk, t_bk, t_Wv, t_bv, kemo, vemo);
  concat_qk_bias<<<dim3(4), 512, 0, stream>>>(b_bq, b_bk, qkbias);
  bias2_p1<<<dim3(16), 256, 0, stream>>>(b_bo, W1, partial);
  bias2_p2<<<dim3(2), 256, 0, stream>>>(b1, partial, bias2);
  sentprep<<<dim3(56), 512, 0, stream>>>(t_Wq, t_bq, t_Wo, kemo, vemo, Wqk_bf, VWo_bf, sbias);
  sentpad<<<dim3(8), 512, 0, stream>>>(Wqk_bf, sbias);
  gemm_bt64<true, 0, 0><<<dim3(8, 4, 4), 256, 0, stream>>>(wT + 14 * SL, bWo_bf, nullptr, Btbig,
                                                           512, 512, 2048, 2048, 512, SL, 512);

  // sentiment block on MFMA: scores -> softmax -> P@VWo -> LN
  gemm_bt64<false, 1, 0><<<dim3(1, 128), 256, 0, stream>>>(xb, Wqk_bf, sbias, scores,
                                                           64, 512, 512, 64, 0, 0, 0);
  softmax7<<<dim3(512), 256, 0, stream>>>(scores, Pmat);
  gemm_bt64<true, 1, 0><<<dim3(8, 128), 256, 0, stream>>>(Pmat, VWo_bf, t_bo, sctx,
                                                          512, 64, 64, 512, 0, 0, 0);
  ln1_bf<<<dim3(16384), 256, 0, stream>>>(sctx, x, t_ln_g, t_ln_b, htb);

  // merged V^T for all 4 branches (col-chunk swizzle: htb panel L2-local)
  gemm32<true, 2, 1><<<dim3(128, 8), 512, 0, stream>>>(wT + 10 * SL, htb, b_bv,
                                                       vtb_all, 16384, 512, 512, 16384);

  // two branch-pairs: merged qkproj (N=2048) + z-merged attention with in-block q-loop
  for (int p = 0; p < 2; ++p) {
    gemm32<true, 1, 0><<<dim3(16, 64), 512, 0, stream>>>(htb, wT + (2 + 4 * p) * SL, qkbias + p * 2048,
                                                         qkb2, 2048, 512, 512, 2048);
    dim3 ag(512, 2);
    if (p == 0) attn_branch<0><<<ag, 256, 0, stream>>>(qkb2, vtb_all, ctxa, lengths, speakers);
    else        attn_branch<1><<<ag, 256, 0, stream>>>(qkb2, vtb_all, ctxa, lengths, speakers);
  }

  // fused (cat @ blockdiag(Wo) @ W1): K=2048
  gemm32<true, 1, 0><<<dim3(4, 64), 512, 0, stream>>>(ctxa, Btbig, bias2, tmpb, 512, 2048, 2048, 512);
  ln2_bb<<<dim3(16384), 256, 0, stream>>>(tmpb, htb, ln2_g, ln2_b, heb);
  gemm32<false, 0, 0><<<dim3(4, 64), 512, 0, stream>>>(heb, wT + 0 * SL, nullptr, (float*)d_out, 512, 512, 512, 512);
}

// Round 19
// 471.840 us; speedup vs baseline: 1.2219x; 1.0209x over previous
//
#include <hip/hip_runtime.h>

#define B_  64
#define T_  256
#define H_  512
#define NH_ 8
#define DH_ 64
#define M_  16384
#define SL  262144  // 512*512 elements per weight slot

typedef float  f32x4 __attribute__((ext_vector_type(4)));
typedef float  f32x2 __attribute__((ext_vector_type(2)));
typedef __bf16 b16x8 __attribute__((ext_vector_type(8)));
typedef __bf16 b16x4 __attribute__((ext_vector_type(4)));
typedef __bf16 b16x2 __attribute__((ext_vector_type(2)));

__device__ __forceinline__ void gload16(const void* g, void* l) {
  __builtin_amdgcn_global_load_lds((const __attribute__((address_space(1))) void*)g,
                                   (__attribute__((address_space(3))) void*)l, 16, 0, 0);
}

// ---------------- fp32 -> bf16 convert ----------------
__global__ __launch_bounds__(256) void cvt_f32_bf16_k(const float* __restrict__ in,
                                                      __bf16* __restrict__ out) {
  size_t i = ((size_t)blockIdx.x * 256 + threadIdx.x) * 4;
  f32x4 v = *(const f32x4*)(in + i);
  b16x4 o;
  o[0] = (__bf16)v[0]; o[1] = (__bf16)v[1]; o[2] = (__bf16)v[2]; o[3] = (__bf16)v[3];
  *(b16x4*)(out + i) = o;
}

// ---------------- batched weight transpose (+ optional scale): up to 15 slices ----------------
struct TP15 { const float* src[15]; int slot[15]; float scl[15]; };
__global__ __launch_bounds__(256) void transpose_cvt15(TP15 p, __bf16* __restrict__ wT) {
  __shared__ float tile[32][33];
  const float* in = p.src[blockIdx.z];
  __bf16* out = wT + (size_t)p.slot[blockIdx.z] * SL;
  const float scl = p.scl[blockIdx.z];
  int c0 = blockIdx.x * 32, r0 = blockIdx.y * 32;
  int tx = threadIdx.x & 31, ty = threadIdx.x >> 5;
  for (int yy = ty; yy < 32; yy += 8)
    tile[yy][tx] = in[(size_t)(r0 + yy) * 512 + c0 + tx];
  __syncthreads();
  for (int yy = ty; yy < 32; yy += 8)
    out[(size_t)(c0 + yy) * 512 + r0 + tx] = (__bf16)(tile[tx][yy] * scl);
}

// ---------------- generic transpose + convert (for W1: 2048x512) ----------------
__global__ __launch_bounds__(256) void transpose_cvt(const float* __restrict__ in,
                                                     __bf16* __restrict__ out, int R, int C) {
  __shared__ float tile[32][33];
  int c0 = blockIdx.x * 32, r0 = blockIdx.y * 32;
  int tx = threadIdx.x & 31, ty = threadIdx.x >> 5;
  for (int yy = ty; yy < 32; yy += 8)
    tile[yy][tx] = in[(size_t)(r0 + yy) * C + c0 + tx];
  __syncthreads();
  for (int yy = ty; yy < 32; yy += 8)
    out[(size_t)(c0 + yy) * R + r0 + tx] = (__bf16)tile[tx][yy];
}

// ---------------- emotion K/V: (7,512) = emo @ W + b ----------------
__global__ __launch_bounds__(512) void emo_kv(const float* __restrict__ emo,
                                              const float* __restrict__ Wk, const float* __restrict__ bk,
                                              const float* __restrict__ Wv, const float* __restrict__ bv,
                                              float* __restrict__ kout, float* __restrict__ vout) {
  int e = blockIdx.x, n = threadIdx.x;
  const float* W = blockIdx.y ? Wv : Wk;
  const float* bb = blockIdx.y ? bv : bk;
  float* o = blockIdx.y ? vout : kout;
  float acc = 0.f;
  for (int kk = 0; kk < 512; ++kk) acc += emo[e * 512 + kk] * W[kk * 512 + n];
  o[e * 512 + n] = acc + bb[n];
}

// ---------------- sentiment precompute (bf16, scale folded) ----------------
__global__ __launch_bounds__(512) void sentprep(const float* __restrict__ Wq,
                                                const float* __restrict__ bq,
                                                const float* __restrict__ Wo,
                                                const float* __restrict__ kemo,
                                                const float* __restrict__ vemo,
                                                __bf16* __restrict__ Wqk_bf,
                                                __bf16* __restrict__ VWo_bf,
                                                float* __restrict__ sbias) {
  const int he = blockIdx.x, h = he / 7, e = he % 7;
  const int t = threadIdx.x;
  const float* kp = kemo + e * 512 + h * 64;
  const float* wqr = Wq + (size_t)t * 512 + h * 64;
  float a = 0.f;
#pragma unroll 8
  for (int d = 0; d < 64; ++d) a += wqr[d] * kp[d];
  Wqk_bf[he * 512 + t] = (__bf16)(a * 0.125f);
  const float* vp = vemo + e * 512 + h * 64;
  float v = 0.f;
#pragma unroll 8
  for (int d = 0; d < 64; ++d) v += vp[d] * Wo[(size_t)(h * 64 + d) * 512 + t];
  VWo_bf[t * 64 + h * 8 + e] = (__bf16)v;
  if (e == 0) VWo_bf[t * 64 + h * 8 + 7] = (__bf16)0.f;
  if (t == 0) {
    float s = 0.f;
    for (int d = 0; d < 64; ++d) s += bq[h * 64 + d] * kp[d];
    sbias[he] = s * 0.125f;
  }
}

__global__ __launch_bounds__(512) void sentpad(__bf16* __restrict__ Wqk_bf,
                                               float* __restrict__ sbias) {
  int r = 56 + blockIdx.x;
  Wqk_bf[r * 512 + threadIdx.x] = (__bf16)0.f;
  if (threadIdx.x == 0) sbias[r] = 0.f;
}

// ---------------- bias helpers; pair layout [bq_{2p}, bk_{2p}*.125, bq_{2p+1}, bk_{2p+1}*.125] ----
__global__ __launch_bounds__(512) void concat_qk_bias(const float* __restrict__ bq,
                                                      const float* __restrict__ bk,
                                                      float* __restrict__ out) {
  int i = blockIdx.x, t = threadIdx.x;
  int base = (i >> 1) * 2048 + (i & 1) * 1024;
  out[base + t]       = bq[i * 512 + t];
  out[base + 512 + t] = bk[i * 512 + t] * 0.125f;
}

__global__ __launch_bounds__(256) void bias2_p1(const float* __restrict__ bo,
                                                const float* __restrict__ W1,
                                                float* __restrict__ partial) {
  int p = blockIdx.x, t = threadIdx.x;
  float a0 = 0.f, a1 = 0.f;
  for (int g = p * 128; g < p * 128 + 128; ++g) {
    float bg = bo[g];
    a0 += bg * W1[(size_t)g * 512 + t];
    a1 += bg * W1[(size_t)g * 512 + 256 + t];
  }
  partial[p * 512 + t] = a0;
  partial[p * 512 + 256 + t] = a1;
}

__global__ __launch_bounds__(256) void bias2_p2(const float* __restrict__ b1,
                                                const float* __restrict__ partial,
                                                float* __restrict__ out) {
  int o = blockIdx.x * 256 + threadIdx.x;
  float acc = b1[o];
#pragma unroll
  for (int p = 0; p < 16; ++p) acc += partial[p * 512 + o];
  out[o] = acc;
}

// ---------------- MFMA GEMM 256x128, 8 waves, BK=32, 2-phase, 48KB LDS ----
// Both output paths use LDS-transposed coalesced epilogues (full-row segments).
template<bool OB, int BM, int SW>
__global__ __launch_bounds__(512, 2) void gemm32(const __bf16* __restrict__ A,
                                                 const __bf16* __restrict__ Bt,
                                                 const float* __restrict__ bias,
                                                 void* __restrict__ Cv,
                                                 int N, int K, int lda, int ldc) {
  __shared__ __attribute__((aligned(16))) __bf16 As[2][256 * 32];
  __shared__ __attribute__((aligned(16))) __bf16 Bs[2][128 * 32];
  const int gx = gridDim.x;
  const int bid = blockIdx.y * gx + blockIdx.x;
  int bx, by;
  if (SW == 0) {
    const int nwg = gx * gridDim.y;
    const int cpx = nwg >> 3;
    const int swz = (bid & 7) * cpx + (bid >> 3);
    bx = swz % gx; by = swz / gx;
  } else {
    const int gxc = gx >> 3;
    const int u = bid >> 3, c = bid & 7;
    bx = c * gxc + u % gxc;
    by = u / gxc;
  }
  const int tid = threadIdx.x, lane = tid & 63, wid = tid >> 6;
  const int wr = wid >> 2, wc = wid & 3;
  const int m0 = by * 256, n0 = bx * 128;
  const int l15 = lane & 15, l16 = lane >> 4;
  const int ra = tid >> 2;
  const int xsl = (tid & 3) ^ ((ra >> 1) & 3);
  const int nt = K >> 5;
  f32x4 acc[8][2] = {};

#define STAGE32(buf, k0)                                                             \
  { char* aw = (char*)&As[buf][0];                                                   \
    char* bw = (char*)&Bs[buf][0];                                                   \
    gload16(A + (size_t)(m0 + ra) * lda + (k0) + xsl * 8, aw + tid * 16);            \
    gload16(A + (size_t)(m0 + 128 + ra) * lda + (k0) + xsl * 8, aw + (512 + tid) * 16); \
    gload16(Bt + (size_t)(n0 + ra) * K + (k0) + xsl * 8, bw + tid * 16); }

#define CMP32(buf)                                                                   \
  { const char* Ac = (const char*)&As[buf][0];                                       \
    const char* Bc = (const char*)&Bs[buf][0];                                       \
    const int swb = ((l16 ^ ((l15 >> 1) & 3)) << 4);                                 \
    b16x8 af[8], bf[2];                                                              \
    _Pragma("unroll")                                                                \
    for (int m = 0; m < 8; ++m)                                                      \
      af[m] = *(const b16x8*)(Ac + (wr * 128 + m * 16 + l15) * 64 + swb);            \
    _Pragma("unroll")                                                                \
    for (int n = 0; n < 2; ++n)                                                      \
      bf[n] = *(const b16x8*)(Bc + (wc * 32 + n * 16 + l15) * 64 + swb);             \
    __builtin_amdgcn_s_setprio(1);                                                   \
    _Pragma("unroll")                                                                \
    for (int m = 0; m < 8; ++m)                                                      \
      _Pragma("unroll")                                                              \
      for (int n = 0; n < 2; ++n)                                                    \
        acc[m][n] = __builtin_amdgcn_mfma_f32_16x16x32_bf16(af[m], bf[n], acc[m][n], 0, 0, 0); \
    __builtin_amdgcn_s_setprio(0); }

  STAGE32(0, 0);
  int cur = 0;
  for (int t = 0; t < nt; ++t) {
    if (t + 1 < nt) {
      STAGE32(cur ^ 1, (t + 1) * 32);
      asm volatile("s_waitcnt vmcnt(3)" ::: "memory");
    } else {
      asm volatile("s_waitcnt vmcnt(0)" ::: "memory");
    }
    __builtin_amdgcn_s_barrier();
    CMP32(cur);
    asm volatile("s_waitcnt lgkmcnt(0)" ::: "memory");
    __builtin_amdgcn_s_barrier();
    cur ^= 1;
  }
#undef STAGE32
#undef CMP32

  const int rb = m0 + wr * 128 + l16 * 4;
  const int cb = n0 + wc * 32 + l15;
  if constexpr (OB) {
    // bf16: wave-private LDS transpose strip (dead As region), 80B row stride.
    __bf16* tb = (__bf16*)((char*)&As[0][0] + wid * 2048);
    const int strow = lane >> 2, sseg = (lane & 3) * 8;
#pragma unroll
    for (int m = 0; m < 8; ++m) {
#pragma unroll
      for (int n = 0; n < 2; ++n) {
        float bc = (BM == 1) ? bias[cb + n * 16] : 0.0f;
#pragma unroll
        for (int rr = 0; rr < 4; ++rr) {
          float val = acc[m][n][rr] + ((BM == 2) ? bias[rb + m * 16 + rr] : bc);
          tb[(l16 * 4 + rr) * 40 + n * 16 + l15] = (__bf16)val;
        }
      }
      asm volatile("s_waitcnt lgkmcnt(0)" ::: "memory");
      b16x8 v = *(const b16x8*)&tb[strow * 40 + sseg];
      *(b16x8*)((__bf16*)Cv + (size_t)(m0 + wr * 128 + m * 16 + strow) * ldc
                + n0 + wc * 32 + sseg) = v;
      asm volatile("s_waitcnt lgkmcnt(0)" ::: "memory");
    }
  } else {
    // fp32: wave-private LDS transpose strip, 144B row stride (36 floats), 2 stores/m-tile.
    float* tb = (float*)((char*)&As[0][0] + wid * 2304);
    const int strow8 = lane >> 3, sseg = (lane & 7) * 4;
#pragma unroll
    for (int m = 0; m < 8; ++m) {
#pragma unroll
      for (int n = 0; n < 2; ++n) {
        float bc = (BM == 1) ? bias[cb + n * 16] : 0.0f;
#pragma unroll
        for (int rr = 0; rr < 4; ++rr) {
          float val = acc[m][n][rr] + ((BM == 2) ? bias[rb + m * 16 + rr] : bc);
          tb[(l16 * 4 + rr) * 36 + n * 16 + l15] = val;
        }
      }
      asm volatile("s_waitcnt lgkmcnt(0)" ::: "memory");
#pragma unroll
      for (int i = 0; i < 2; ++i) {
        int r = strow8 + 8 * i;
        f32x4 v = *(const f32x4*)&tb[r * 36 + sseg];
        *(f32x4*)((float*)Cv + (size_t)(m0 + wr * 128 + m * 16 + r) * ldc
                  + n0 + wc * 32 + sseg) = v;
      }
      asm volatile("s_waitcnt lgkmcnt(0)" ::: "memory");
    }
  }
}

// ---------------- MFMA GEMM 128x64 (proven; small/odd shapes, z-batched) ----------------
template<bool OB, int BM, int SW>
__global__ __launch_bounds__(256) void gemm_bt64(const __bf16* __restrict__ A,
                                                 const __bf16* __restrict__ Bt,
                                                 const float* __restrict__ bias,
                                                 void* __restrict__ Cv,
                                                 int N, int K, int lda, int ldc,
                                                 size_t zA, size_t zB, size_t zC) {
  __shared__ __attribute__((aligned(16))) __bf16 As[128 * 32];
  __shared__ __attribute__((aligned(16))) __bf16 Bs[64 * 32];
  A  += (size_t)blockIdx.z * zA;
  Bt += (size_t)blockIdx.z * zB;
  char* Cb = (char*)Cv + (size_t)blockIdx.z * zC * (OB ? 2 : 4);
  const int gx = gridDim.x;
  const int bid = blockIdx.y * gx + blockIdx.x;
  int bx, by;
  if (SW == 0) {
    const int nwg = gx * gridDim.y;
    const int cpx = nwg >> 3;
    const int swz = (bid & 7) * cpx + (bid >> 3);
    bx = swz % gx; by = swz / gx;
  } else {
    const int gxc = gx >> 3;
    const int u = bid >> 3, c = bid & 7;
    bx = c * gxc + u % gxc;
    by = u / gxc;
  }
  const int tid = threadIdx.x, lane = tid & 63, wid = tid >> 6;
  const int m0 = by * 128, n0 = bx * 64;
  const int l15 = lane & 15, l16 = lane >> 4;
  const int r0 = tid >> 2, o0 = (tid & 3) * 8;
  const __bf16* a0 = A + (size_t)(m0 + r0) * lda + o0;
  const __bf16* a1 = A + (size_t)(m0 + 64 + r0) * lda + o0;
  const __bf16* bp0 = Bt + (size_t)(n0 + r0) * K + o0;
  char* AsW = (char*)As + wid * 1024;
  char* BsW = (char*)Bs + wid * 1024;
  f32x4 acc[2][4] = {};
  for (int k0 = 0; k0 < K; k0 += 32) {
    gload16(a0 + k0, AsW);
    gload16(a1 + k0, AsW + 4096);
    gload16(bp0 + k0, BsW);
    __syncthreads();
    b16x8 af[2], bf[4];
#pragma unroll
    for (int m = 0; m < 2; ++m) af[m] = *(const b16x8*)&As[(wid * 32 + m * 16 + l15) * 32 + l16 * 8];
#pragma unroll
    for (int n = 0; n < 4; ++n) bf[n] = *(const b16x8*)&Bs[(n * 16 + l15) * 32 + l16 * 8];
#pragma unroll
    for (int m = 0; m < 2; ++m)
#pragma unroll
      for (int n = 0; n < 4; ++n)
        acc[m][n] = __builtin_amdgcn_mfma_f32_16x16x32_bf16(af[m], bf[n], acc[m][n], 0, 0, 0);
    __syncthreads();
  }
  const int rbase = m0 + wid * 32 + l16 * 4;
  const int cb = n0 + l15;
#pragma unroll
  for (int n = 0; n < 4; ++n) {
    int gc = cb + n * 16;
    float bc = (BM == 1) ? bias[gc] : 0.0f;
#pragma unroll
    for (int m = 0; m < 2; ++m) {
#pragma unroll
      for (int rr = 0; rr < 4; ++rr) {
        int gr = rbase + m * 16 + rr;
        float val = acc[m][n][rr] + ((BM == 2) ? bias[gr] : bc);
        if (OB) ((__bf16*)Cb)[(size_t)gr * ldc + gc] = (__bf16)val;
        else    ((float*)Cb)[(size_t)gr * ldc + gc] = val;
      }
    }
  }
}

// ---------------- per-(token,head) 7-wide softmax ----------------
__global__ __launch_bounds__(256) void softmax7(const float* __restrict__ scores,
                                                __bf16* __restrict__ P) {
  int idx = blockIdx.x * 256 + threadIdx.x;
  int m = idx >> 3, h = idx & 7;
  const float* s = scores + (size_t)m * 64 + h * 7;
  float v[7], mx = -3.4e38f;
#pragma unroll
  for (int e = 0; e < 7; ++e) { v[e] = s[e]; mx = fmaxf(mx, v[e]); }
  float sum = 0.f;
#pragma unroll
  for (int e = 0; e < 7; ++e) { v[e] = __expf(v[e] - mx); sum += v[e]; }
  float inv = 1.f / sum;
  __bf16* o = P + (size_t)m * 64 + h * 8;
#pragma unroll
  for (int e = 0; e < 7; ++e) o[e] = (__bf16)(v[e] * inv);
  o[7] = (__bf16)0.f;
}

// ---------------- bf16 pre + fp32 res LayerNorm -> bf16 (128 thr x 4 elems) ----------------
__global__ __launch_bounds__(128) void ln1_bf(const __bf16* __restrict__ pre,
                                              const float* __restrict__ res,
                                              const float* __restrict__ g,
                                              const float* __restrict__ bt,
                                              __bf16* __restrict__ ob) {
  int row = blockIdx.x, t = threadIdx.x;
  size_t base = (size_t)row * 512;
  b16x4 p4 = *(const b16x4*)(pre + base + 4 * t);
  f32x4 r4 = *(const f32x4*)(res + base + 4 * t);
  float v[4];
  float s = 0.f, q = 0.f;
#pragma unroll
  for (int i = 0; i < 4; ++i) {
    v[i] = (float)p4[i] + r4[i];
    s += v[i]; q += v[i] * v[i];
  }
#pragma unroll
  for (int off = 32; off; off >>= 1) { s += __shfl_xor(s, off); q += __shfl_xor(q, off); }
  __shared__ float ls[2], lq[2];
  int w = t >> 6, lane = t & 63;
  if (lane == 0) { ls[w] = s; lq[w] = q; }
  __syncthreads();
  s = ls[0] + ls[1];
  q = lq[0] + lq[1];
  float mean = s * (1.f / 512.f);
  float var = q * (1.f / 512.f) - mean * mean;
  float rstd = rsqrtf(fmaxf(var, 0.f) + 1e-12f);
  f32x4 g4 = *(const f32x4*)(g + 4 * t);
  f32x4 b4 = *(const f32x4*)(bt + 4 * t);
  b16x4 o;
#pragma unroll
  for (int i = 0; i < 4; ++i) o[i] = (__bf16)((v[i] - mean) * rstd * g4[i] + b4[i]);
  *(b16x4*)(ob + base + 4 * t) = o;
}

// ---------------- bf16+bf16 residual LayerNorm (128 thr x 4 elems) ----------------
__global__ __launch_bounds__(128) void ln2_bb(const __bf16* __restrict__ pre,
                                              const __bf16* __restrict__ res,
                                              const float* __restrict__ g,
                                              const float* __restrict__ bt,
                                              __bf16* __restrict__ ob) {
  int row = blockIdx.x, t = threadIdx.x;
  size_t base = (size_t)row * 512;
  b16x4 p4 = *(const b16x4*)(pre + base + 4 * t);
  b16x4 r4 = *(const b16x4*)(res + base + 4 * t);
  float v[4];
  float s = 0.f, q = 0.f;
#pragma unroll
  for (int i = 0; i < 4; ++i) {
    v[i] = (float)p4[i] + (float)r4[i];
    s += v[i]; q += v[i] * v[i];
  }
#pragma unroll
  for (int off = 32; off; off >>= 1) { s += __shfl_xor(s, off); q += __shfl_xor(q, off); }
  __shared__ float ls[2], lq[2];
  int w = t >> 6, lane = t & 63;
  if (lane == 0) { ls[w] = s; lq[w] = q; }
  __syncthreads();
  s = ls[0] + ls[1];
  q = lq[0] + lq[1];
  float mean = s * (1.f / 512.f);
  float var = q * (1.f / 512.f) - mean * mean;
  float rstd = rsqrtf(fmaxf(var, 0.f) + 1e-12f);
  f32x4 g4 = *(const f32x4*)(g + 4 * t);
  f32x4 b4 = *(const f32x4*)(bt + 4 * t);
  b16x4 o;
#pragma unroll
  for (int i = 0; i < 4; ++i) o[i] = (__bf16)((v[i] - mean) * rstd * g4[i] + b4[i]);
  *(b16x4*)(ob + base + 4 * t) = o;
}

// ---------------- fused masked attention: K once, q-loop inside, FIXED-MAX softmax ----------------
template<int PAIR>
__global__ __launch_bounds__(256, 4) void attn_branch(const __bf16* __restrict__ qk,
                                                      const __bf16* __restrict__ vt,
                                                      __bf16* __restrict__ ctx,
                                                      const int* __restrict__ lengths,
                                                      const int* __restrict__ speakers) {
  __shared__ __attribute__((aligned(16))) __bf16 Ks[256 * 64];
  __shared__ __attribute__((aligned(16))) __bf16 Ps[32 * 264];
  __shared__ float redS[2][32];
  __shared__ int spk[256];
  const int sqk = 2048, so = 2048;
  const int tid = threadIdx.x, lane = tid & 63, wid = tid >> 6;
  const int l15 = lane & 15, l16 = lane >> 4;
  const int bh = blockIdx.x, z = blockIdx.y;
  const int BR = PAIR * 2 + z;
  const int b = bh >> 3, h = bh & 7;
  const int wq = wid & 1, wk = wid >> 1;
  const int mh = wid & 1, nh = wid >> 1;
  const __bf16* qp = qk + z * 1024;
  const __bf16* kp = qp + 512;
  const __bf16* vb2 = vt + (size_t)(BR * 512 + h * DH_) * M_ + b * T_;
  __bf16* ctxp = ctx + (size_t)BR * 512;
  const __bf16 CB = (__bf16)10000.0f, mCB = (__bf16)(-10000.0f), ZB = (__bf16)0.0f, OB1 = (__bf16)1.0f;
  const float CBF = (float)CB;
  const float MSTAR = (BR == 1) ? 16.0f : CBF + 16.0f;

  {
    const size_t kb0 = (size_t)(b * T_) * sqk + h * DH_;
    const int rsub = lane >> 3, slot = lane & 7;
#pragma unroll
    for (int j = 0; j < 8; ++j) {
      int row = (j * 4 + wid) * 8 + rsub;
      gload16(kp + kb0 + (size_t)row * sqk + ((slot ^ (row & 7)) * 8),
              (char*)Ks + (j * 4 + wid) * 1024);
    }
  }
  spk[tid] = speakers[b * T_ + tid];
  __syncthreads();
  const int L = lengths[b];

  b16x8 af0, af1;
  {
    const __bf16* qr = qp + (size_t)(b * T_ + wq * 16 + l15) * sqk + h * DH_;
    af0 = *(const b16x8*)(qr + l16 * 8);
    af1 = *(const b16x8*)(qr + 32 + l16 * 8);
  }

  for (int qc = 0; qc < 8; ++qc) {
    const int q0 = qc * 32;
    b16x8 afU = {};
    if (BR != 1 && l16 == 0) {
      int jA = q0 + wq * 16 + l15;
      bool rv = jA < L;
      afU[0] = rv ? OB1 : ZB;
      afU[1] = (rv && spk[jA]) ? OB1 : ZB;
      afU[2] = (BR == 0) ? OB1 : (rv ? ZB : OB1);
    }

    f32x4 sa[4][2] = {};
#pragma unroll
    for (int kc = 0; kc < 4; ++kc) {
#pragma unroll
      for (int nn = 0; nn < 2; ++nn) {
        int krw = kc * 64 + wk * 32 + nn * 16 + l15;
        b16x8 b0 = *(const b16x8*)((char*)Ks + krw * 128 + ((l16 ^ (krw & 7)) * 16));
        sa[kc][nn] = __builtin_amdgcn_mfma_f32_16x16x32_bf16(af0, b0, sa[kc][nn], 0, 0, 0);
        b16x8 b1 = *(const b16x8*)((char*)Ks + krw * 128 + (((4 + l16) ^ (krw & 7)) * 16));
        sa[kc][nn] = __builtin_amdgcn_mfma_f32_16x16x32_bf16(af1, b1, sa[kc][nn], 0, 0, 0);
        if (BR != 1) {
          b16x8 w = {};
          if (l16 == 0) {
            bool cv = krw < L;
            int sc = spk[krw];
            if (BR == 0) {
              w[2] = cv ? CB : ZB;
            } else if (BR == 2) {
              w[0] = sc ? ZB : CB;
              w[1] = sc ? CB : mCB;
              w[2] = CB;
            } else {
              w[0] = (cv && sc) ? CB : ZB;
              w[1] = cv ? (sc ? mCB : CB) : ZB;
              w[2] = CB;
            }
          }
          sa[kc][nn] = __builtin_amdgcn_mfma_f32_16x16x32_bf16(afU, w, sa[kc][nn], 0, 0, 0);
        }
      }
    }

    if (qc + 1 < 8) {
      const __bf16* qr = qp + (size_t)(b * T_ + (qc + 1) * 32 + wq * 16 + l15) * sqk + h * DH_;
      af0 = *(const b16x8*)(qr + l16 * 8);
      af1 = *(const b16x8*)(qr + 32 + l16 * 8);
    }

    const int rloc = wq * 16 + l16 * 4;
    float sm[4];
#pragma unroll
    for (int rr = 0; rr < 4; ++rr) {
      const int j = q0 + rloc + rr;
      const bool rv = j < L;
      float s = 0.f;
#pragma unroll
      for (int kc = 0; kc < 4; ++kc)
#pragma unroll
        for (int nn = 0; nn < 2; ++nn) {
          float v = sa[kc][nn][rr];
          if (BR == 1) {
            int c = kc * 64 + wk * 32 + nn * 16 + l15;
            int dj = j - c;
            bool ok = (c < L) && (dj <= 2) && (dj >= -2);
            v += (ok || !rv) ? 0.0f : -10000.0f;
          }
          float e = __expf(v - MSTAR);
          sa[kc][nn][rr] = e;
          s += e;
        }
      s += __shfl_xor(s, 1); s += __shfl_xor(s, 2); s += __shfl_xor(s, 4); s += __shfl_xor(s, 8);
      sm[rr] = s;
    }
#pragma unroll
    for (int rr = 0; rr < 4; ++rr) {
      if (l15 == 0) redS[wk][rloc + rr] = sm[rr];
#pragma unroll
      for (int kc = 0; kc < 4; ++kc)
#pragma unroll
        for (int nn = 0; nn < 2; ++nn)
          Ps[(rloc + rr) * 264 + kc * 64 + wk * 32 + nn * 16 + l15] = (__bf16)sa[kc][nn][rr];
    }
    __syncthreads();

    f32x4 oa[2] = {};
#pragma unroll
    for (int kt = 0; kt < 8; ++kt) {
      b16x8 afp = *(const b16x8*)(Ps + (mh * 16 + l15) * 264 + kt * 32 + l16 * 8);
#pragma unroll
      for (int n = 0; n < 2; ++n) {
        int d = nh * 32 + n * 16 + l15;
        b16x8 bfr = *(const b16x8*)(vb2 + (size_t)d * M_ + kt * 32 + l16 * 8);
        oa[n] = __builtin_amdgcn_mfma_f32_16x16x32_bf16(afp, bfr, oa[n], 0, 0, 0);
      }
    }
#pragma unroll
    for (int rr = 0; rr < 4; ++rr) {
      int row = mh * 16 + l16 * 4 + rr;
      float rinv = 1.0f / (redS[0][row] + redS[1][row]);
#pragma unroll
      for (int n = 0; n < 2; ++n)
        ctxp[(size_t)(b * T_ + q0 + row) * so + h * DH_ + nh * 32 + n * 16 + l15]
            = (__bf16)(oa[n][rr] * rinv);
    }
    __syncthreads();
  }
}

// ============================================================================
extern "C" void kernel_launch(void* const* d_in, const int* in_sizes, int n_in,
                              void* d_out, int out_size, void* d_ws, size_t ws_size,
                              hipStream_t stream) {
  const float* x        = (const float*)d_in[0];
  const int*   lengths  = (const int*)d_in[1];
  const int*   speakers = (const int*)d_in[2];
  const float* emo      = (const float*)d_in[3];
  const float* t_Wq = (const float*)d_in[4];
  const float* t_bq = (const float*)d_in[5];
  const float* t_Wk = (const float*)d_in[6];
  const float* t_bk = (const float*)d_in[7];
  const float* t_Wv = (const float*)d_in[8];
  const float* t_bv = (const float*)d_in[9];
  const float* t_Wo = (const float*)d_in[10];
  const float* t_bo = (const float*)d_in[11];
  const float* t_ln_g = (const float*)d_in[12];
  const float* t_ln_b = (const float*)d_in[13];
  const float* b_Wq = (const float*)d_in[14];
  const float* b_bq = (const float*)d_in[15];
  const float* b_Wk = (const float*)d_in[16];
  const float* b_bk = (const float*)d_in[17];
  const float* b_Wv = (const float*)d_in[18];
  const float* b_bv = (const float*)d_in[19];
  const float* b_Wo = (const float*)d_in[20];
  const float* b_bo = (const float*)d_in[21];
  const float* W1   = (const float*)d_in[22];
  const float* b1   = (const float*)d_in[23];
  const float* ln2_g = (const float*)d_in[24];
  const float* ln2_b = (const float*)d_in[25];
  const float* W2   = (const float*)d_in[26];

  if (ws_size < 232314880) return;

  char* ws = (char*)d_ws;
  // wT slots: 0=W2t  [2+2i]=WqT_i [3+2i]=WkT_i(x0.125)  [10+i]=WvT_i  14..17=W1t
  __bf16* wT      = (__bf16*)(ws);
  __bf16* bWo_bf  = (__bf16*)(ws + 9437184);
  __bf16* Btbig   = (__bf16*)(ws + 11534336);
  float*  qkbias  = (float*)(ws + 13631488);
  float*  bias2   = (float*)(ws + 13647872);
  float*  kemo    = (float*)(ws + 13649920);
  float*  vemo    = (float*)(ws + 13664256);
  __bf16* Wqk_bf  = (__bf16*)(ws + 13678592);
  __bf16* VWo_bf  = (__bf16*)(ws + 13744128);
  float*  sbias   = (float*)(ws + 13809664);
  __bf16* htb     = (__bf16*)(ws + 13908224);
  __bf16* qkb2    = (__bf16*)(ws + 30685440);   // [16384][2048]
  __bf16* vtb_all = (__bf16*)(ws + 97794304);   // [2048][16384]
  __bf16* ctxa    = (__bf16*)(ws + 164903168);  // [16384][2048]
  // overlays
  __bf16* xb      = (__bf16*)(ws + 164903168);
  float*  partial = (float*)(ws + 30685440);
  float*  scores  = (float*)(ws + 30685440);
  __bf16* Pmat    = (__bf16*)(ws + 30685440 + 4194304);
  __bf16* sctx    = (__bf16*)(ws + 30685440 + 8388608);
  __bf16* tmpb    = qkb2;
  __bf16* heb     = (__bf16*)(ws + 47462656);

  // conversions + transposes
  cvt_f32_bf16_k<<<dim3(8192), 256, 0, stream>>>(x, xb);
  cvt_f32_bf16_k<<<dim3(1024), 256, 0, stream>>>(b_Wo, bWo_bf);
  {
    TP15 p;
    const float* srcs[13] = {b_Wq, b_Wq + SL, b_Wq + 2 * SL, b_Wq + 3 * SL,
                             b_Wk, b_Wk + SL, b_Wk + 2 * SL, b_Wk + 3 * SL,
                             b_Wv, b_Wv + SL, b_Wv + 2 * SL, b_Wv + 3 * SL,
                             W2};
    const int slots[13] = {2, 4, 6, 8, 3, 5, 7, 9, 10, 11, 12, 13, 0};
    for (int i = 0; i < 13; ++i) {
      p.src[i] = srcs[i]; p.slot[i] = slots[i];
      p.scl[i] = (i >= 4 && i < 8) ? 0.125f : 1.0f;
    }
    for (int i = 13; i < 15; ++i) { p.src[i] = W2; p.slot[i] = 0; p.scl[i] = 1.0f; }
    transpose_cvt15<<<dim3(16, 16, 13), 256, 0, stream>>>(p, wT);
  }
  transpose_cvt<<<dim3(16, 64), 256, 0, stream>>>(W1, wT + 14 * SL, 2048, 512);
  emo_kv<<<dim3(7, 2), 512, 0, stream>>>(emo, t_Wk, t_bk, t_Wv, t_bv, kemo, vemo);
  concat_qk_bias<<<dim3(4), 512, 0, stream>>>(b_bq, b_bk, qkbias);
  bias2_p1<<<dim3(16), 256, 0, stream>>>(b_bo, W1, partial);
  bias2_p2<<<dim3(2), 256, 0, stream>>>(b1, partial, bias2);
  sentprep<<<dim3(56), 512, 0, stream>>>(t_Wq, t_bq, t_Wo, kemo, vemo, Wqk_bf, VWo_bf, sbias);
  sentpad<<<dim3(8), 512, 0, stream>>>(Wqk_bf, sbias);
  gemm_bt64<true, 0, 0><<<dim3(8, 4, 4), 256, 0, stream>>>(wT + 14 * SL, bWo_bf, nullptr, Btbig,
                                                           512, 512, 2048, 2048, 512, SL, 512);

  // sentiment block on MFMA: scores -> softmax -> P@VWo -> LN
  gemm_bt64<false, 1, 0><<<dim3(1, 128), 256, 0, stream>>>(xb, Wqk_bf, sbias, scores,
                                                           64, 512, 512, 64, 0, 0, 0);
  softmax7<<<dim3(512), 256, 0, stream>>>(scores, Pmat);
  gemm_bt64<true, 1, 0><<<dim3(8, 128), 256, 0, stream>>>(Pmat, VWo_bf, t_bo, sctx,
                                                          512, 64, 64, 512, 0, 0, 0);
  ln1_bf<<<dim3(16384), 128, 0, stream>>>(sctx, x, t_ln_g, t_ln_b, htb);

  // merged V^T for all 4 branches (col-chunk swizzle: htb panel L2-local)
  gemm32<true, 2, 1><<<dim3(128, 8), 512, 0, stream>>>(wT + 10 * SL, htb, b_bv,
                                                       vtb_all, 16384, 512, 512, 16384);

  // two branch-pairs: merged qkproj (N=2048) + z-merged attention with in-block q-loop
  for (int p = 0; p < 2; ++p) {
    gemm32<true, 1, 0><<<dim3(16, 64), 512, 0, stream>>>(htb, wT + (2 + 4 * p) * SL, qkbias + p * 2048,
                                                         qkb2, 2048, 512, 512, 2048);
    dim3 ag(512, 2);
    if (p == 0) attn_branch<0><<<ag, 256, 0, stream>>>(qkb2, vtb_all, ctxa, lengths, speakers);
    else        attn_branch<1><<<ag, 256, 0, stream>>>(qkb2, vtb_all, ctxa, lengths, speakers);
  }

  // fused (cat @ blockdiag(Wo) @ W1): K=2048
  gemm32<true, 1, 0><<<dim3(4, 64), 512, 0, stream>>>(ctxa, Btbig, bias2, tmpb, 512, 2048, 2048, 512);
  ln2_bb<<<dim3(16384), 128, 0, stream>>>(tmpb, htb, ln2_g, ln2_b, heb);
  gemm32<false, 0, 0><<<dim3(4, 64), 512, 0, stream>>>(heb, wT + 0 * SL, nullptr, (float*)d_out, 512, 512, 512, 512);
}